// Round 2
// baseline (3273.783 us; speedup 1.0000x reference)
//
#include <hip/hip_runtime.h>
#include <math.h>

// DIEN: B=4096, T=50, D=U=128. Full fp32 correctness-first baseline.
// ws layout (floats): hs[B*T*128] | ats[B*T] | hf[B*128] | Wp[128*384] | Up[128*384] | bp[384]
// total = 27,042,176 floats = 108.2 MB.

#define Bsz 4096
#define Tt  50
#define Dd  128
#define Uu  128
#define GN  384
#define LK  0.0003f

__device__ __forceinline__ float sigf(float x) { return 1.0f / (1.0f + expf(-x)); }
__device__ __forceinline__ void fma4(float4& a, float s, const float4& w) {
    a.x += s * w.x; a.y += s * w.y; a.z += s * w.z; a.w += s * w.w;
}
__device__ __forceinline__ float lky(float v) { return v >= 0.0f ? v : LK * v; }

// ---------------- pack AUGRU weights into fused [128][384] panels ----------------
__global__ void pack_augru(const float* __restrict__ Wu_, const float* __restrict__ Wr_,
                           const float* __restrict__ Wc_, const float* __restrict__ Uug_,
                           const float* __restrict__ Urg_, const float* __restrict__ Ucg_,
                           const float* __restrict__ bu_, const float* __restrict__ br_,
                           const float* __restrict__ bc_,
                           float* __restrict__ Wp, float* __restrict__ Up, float* __restrict__ bp)
{
    int i = blockIdx.x * blockDim.x + threadIdx.x;
    if (i < Uu * GN) {
        int k = i / GN, c = i % GN;
        int g = c >> 7, cc = c & 127;
        const float* W  = (g == 0) ? Wu_  : (g == 1) ? Wr_  : Wc_;
        const float* Ug = (g == 0) ? Uug_ : (g == 1) ? Urg_ : Ucg_;
        Wp[i] = W[k * Uu + cc];
        Up[i] = Ug[k * Uu + cc];
    }
    if (i < GN) {
        const float* bb = (i < 128) ? bu_ : (i < 256) ? br_ : bc_;
        bp[i] = bb[i & 127];
    }
}

// ---------------- GRU: fused projection + recurrence ----------------
// 16 rows/block, 256 threads = 8 rgroups(2 rows) x 32 cgroups(12 cols)
__global__ __launch_bounds__(256) void gru_fused(
    const float* __restrict__ inputs, const float* __restrict__ W,
    const float* __restrict__ Ug, const float* __restrict__ bb,
    float* __restrict__ hs)
{
    __shared__ float4 h4[16 * 32];      // h   [16][128]
    __shared__ float4 x4[16 * 32];      // x_t [16][128]
    __shared__ float4 Wt4[32 * 96];     // W tile [32][384]; overlay sx [16][384]
    __shared__ float4 Ut4[32 * 96];     // U tile [32][384]; overlay sh [16][384]
    float* h_l = (float*)h4;
    float* x_l = (float*)x4;
    float* Wt  = (float*)Wt4;
    float* Ut  = (float*)Ut4;
    float* sx  = Wt;
    float* sh  = Ut;

    const int tid = threadIdx.x;
    const int rg  = tid >> 5;          // 0..7
    const int cg  = tid & 31;          // 0..31
    const int rr0 = rg * 2;
    const int c0  = cg * 12;
    const size_t row0 = (size_t)blockIdx.x * 16;

    float b0r[12], b1r[12];
#pragma unroll
    for (int j = 0; j < 12; ++j) { b0r[j] = bb[c0 + j]; b1r[j] = bb[GN + c0 + j]; }

    for (int i = tid; i < 16 * 32; i += 256) h4[i] = make_float4(0, 0, 0, 0);

    for (int t = 0; t < Tt; ++t) {
        __syncthreads();  // h_l writes (prev gate pass) & sx/sh reads done
        for (int i = tid; i < 16 * 32; i += 256) {
            int r = i >> 5, q = i & 31;
            x4[i] = *(const float4*)&inputs[((row0 + r) * (Tt + 1) + t) * Dd + q * 4];
        }
        float4 accx[2][3], acch[2][3];
#pragma unroll
        for (int i = 0; i < 2; ++i)
#pragma unroll
            for (int q = 0; q < 3; ++q) { accx[i][q] = make_float4(0,0,0,0); acch[i][q] = make_float4(0,0,0,0); }

        for (int kt = 0; kt < 4; ++kt) {
            __syncthreads();
            for (int i = tid; i < 32 * 96; i += 256) {
                Wt4[i] = *((const float4*)(W  + kt * 32 * GN) + i);
                Ut4[i] = *((const float4*)(Ug + kt * 32 * GN) + i);
            }
            __syncthreads();
#pragma unroll 4
            for (int k = 0; k < 32; ++k) {
                const int kk = kt * 32 + k;
                float ax0 = x_l[rr0 * 128 + kk];
                float ax1 = x_l[(rr0 + 1) * 128 + kk];
                float ah0 = h_l[rr0 * 128 + kk];
                float ah1 = h_l[(rr0 + 1) * 128 + kk];
                float4 w0 = *(const float4*)&Wt[k * GN + c0];
                float4 w1 = *(const float4*)&Wt[k * GN + c0 + 4];
                float4 w2 = *(const float4*)&Wt[k * GN + c0 + 8];
                float4 u0 = *(const float4*)&Ut[k * GN + c0];
                float4 u1 = *(const float4*)&Ut[k * GN + c0 + 4];
                float4 u2 = *(const float4*)&Ut[k * GN + c0 + 8];
                fma4(accx[0][0], ax0, w0); fma4(accx[0][1], ax0, w1); fma4(accx[0][2], ax0, w2);
                fma4(accx[1][0], ax1, w0); fma4(accx[1][1], ax1, w1); fma4(accx[1][2], ax1, w2);
                fma4(acch[0][0], ah0, u0); fma4(acch[0][1], ah0, u1); fma4(acch[0][2], ah0, u2);
                fma4(acch[1][0], ah1, u0); fma4(acch[1][1], ah1, u1); fma4(acch[1][2], ah1, u2);
            }
        }
        __syncthreads();  // tiles consumed; overlay with sx/sh
#pragma unroll
        for (int i = 0; i < 2; ++i) {
#pragma unroll
            for (int q = 0; q < 3; ++q) {
                float4 vx = accx[i][q];
                vx.x += b0r[q*4+0]; vx.y += b0r[q*4+1]; vx.z += b0r[q*4+2]; vx.w += b0r[q*4+3];
                *(float4*)&sx[(rr0 + i) * GN + c0 + q * 4] = vx;
                float4 vh = acch[i][q];
                vh.x += b1r[q*4+0]; vh.y += b1r[q*4+1]; vh.z += b1r[q*4+2]; vh.w += b1r[q*4+3];
                *(float4*)&sh[(rr0 + i) * GN + c0 + q * 4] = vh;
            }
        }
        __syncthreads();
        for (int i = tid; i < 16 * 128; i += 256) {
            int r = i >> 7, u = i & 127;
            float xz = sx[r * GN + u], xr = sx[r * GN + 128 + u], xh = sx[r * GN + 256 + u];
            float hz = sh[r * GN + u], hr = sh[r * GN + 128 + u], hh = sh[r * GN + 256 + u];
            float z  = sigf(xz + hz);
            float rga = sigf(xr + hr);
            float hc = tanhf(xh + rga * hh);
            float hn = z * h_l[r * 128 + u] + (1.0f - z) * hc;
            h_l[r * 128 + u] = hn;
            hs[((row0 + r) * Tt + t) * Uu + u] = hn;
        }
    }
}

// ---------------- attention MLP (fully fused), 32 rows/block ----------------
__global__ __launch_bounds__(256) void attn_kernel(
    const float* __restrict__ hs, const float* __restrict__ inputs,
    const float* __restrict__ W1, const float* __restrict__ b1,
    const float* __restrict__ W2, const float* __restrict__ b2,
    const float* __restrict__ W3, const float* __restrict__ b3,
    float* __restrict__ ats)
{
    __shared__ float4 emb4[32 * 128];   // [32][512]  64KB
    __shared__ float4 W1t4[64 * 32];    // [64][128]  32KB
    __shared__ float4 a1l4[32 * 32];    // [32][128]  16KB
    __shared__ float4 W2l4[128 * 16];   // [128][64]  32KB
    __shared__ float  a2l[32][66];
    __shared__ float  w3l[64];
    float* emb = (float*)emb4; float* W1t = (float*)W1t4;
    float* a1l = (float*)a1l4; float* W2l = (float*)W2l4;

    const int tid = threadIdx.x;
    const size_t r0 = (size_t)blockIdx.x * 32;

    for (int i = tid; i < 32 * 32; i += 256) {
        int r = i >> 5, q = i & 31;
        *(float4*)&emb[r * 512 + q * 4] = *(const float4*)&hs[(r0 + r) * 128 + q * 4];
    }
    for (int i = tid; i < 32 * 32; i += 256) {
        int r = i >> 5, q = i & 31;
        size_t b = (r0 + r) / Tt;
        *(float4*)&emb[r * 512 + 256 + q * 4] =
            *(const float4*)&inputs[(b * (Tt + 1) + Tt) * Dd + q * 4];
    }
    for (int i = tid; i < 128 * 16; i += 256) W2l4[i] = ((const float4*)W2)[i];
    if (tid < 64) w3l[tid] = W3[tid];
    __syncthreads();
    for (int i = tid; i < 32 * 128; i += 256) {
        int r = i >> 7, c = i & 127;
        float hv = emb[r * 512 + c], nv = emb[r * 512 + 256 + c];
        emb[r * 512 + 128 + c] = nv - hv;
        emb[r * 512 + 384 + c] = hv * nv;
    }

    const int rg = tid >> 5;   // 4 rows each
    const int cg = tid & 31;   // 4 cols each
    float b1r[4];
#pragma unroll
    for (int j = 0; j < 4; ++j) b1r[j] = b1[cg * 4 + j];
    float4 acc1[4];
#pragma unroll
    for (int i = 0; i < 4; ++i) acc1[i] = make_float4(0,0,0,0);

    for (int kt = 0; kt < 8; ++kt) {
        __syncthreads();
        for (int i = tid; i < 64 * 32; i += 256)
            W1t4[i] = *((const float4*)(W1 + kt * 64 * 128) + i);
        __syncthreads();
#pragma unroll 4
        for (int k = 0; k < 64; ++k) {
            float4 w = *(const float4*)&W1t[k * 128 + cg * 4];
#pragma unroll
            for (int i = 0; i < 4; ++i) {
                float e = emb[(rg * 4 + i) * 512 + kt * 64 + k];
                fma4(acc1[i], e, w);
            }
        }
    }
    __syncthreads();
#pragma unroll
    for (int i = 0; i < 4; ++i) {
        float4 v = acc1[i];
        v.x = fmaxf(v.x + b1r[0], 0.f); v.y = fmaxf(v.y + b1r[1], 0.f);
        v.z = fmaxf(v.z + b1r[2], 0.f); v.w = fmaxf(v.w + b1r[3], 0.f);
        *(float4*)&a1l[(rg * 4 + i) * 128 + cg * 4] = v;
    }
    __syncthreads();

    // phase 2: a2 = relu(a1 @ W2 + b2); cols: cg -> {cg*2, cg*2+1}
    float acc2[4][2] = {};
#pragma unroll 4
    for (int k = 0; k < 128; ++k) {
        float w0 = W2l[k * 64 + cg * 2], w1 = W2l[k * 64 + cg * 2 + 1];
#pragma unroll
        for (int i = 0; i < 4; ++i) {
            float a = a1l[(rg * 4 + i) * 128 + k];
            acc2[i][0] += a * w0; acc2[i][1] += a * w1;
        }
    }
    float b2r0 = b2[cg * 2], b2r1 = b2[cg * 2 + 1];
#pragma unroll
    for (int i = 0; i < 4; ++i) {
        a2l[rg * 4 + i][cg * 2]     = fmaxf(acc2[i][0] + b2r0, 0.f);
        a2l[rg * 4 + i][cg * 2 + 1] = fmaxf(acc2[i][1] + b2r1, 0.f);
    }
    __syncthreads();

    if (tid < 32) {
        float s = b3[0];
#pragma unroll 8
        for (int k = 0; k < 64; ++k) s += a2l[tid][k] * w3l[k];
        ats[r0 + tid] = sigf(s);
    }
}

// ---------------- AUGRU: fused projection + attention-gated recurrence ----------------
__global__ __launch_bounds__(256) void augru_fused(
    const float* __restrict__ hs, const float* __restrict__ Wp,
    const float* __restrict__ Up, const float* __restrict__ bp,
    const float* __restrict__ ats, float* __restrict__ hf)
{
    __shared__ float4 h4[16 * 32];
    __shared__ float4 x4[16 * 32];
    __shared__ float4 Wt4[32 * 96];
    __shared__ float4 Ut4[32 * 96];
    __shared__ float  at_l[16];
    float* h_l = (float*)h4;
    float* x_l = (float*)x4;
    float* Wt  = (float*)Wt4;
    float* Ut  = (float*)Ut4;
    float* sx  = Wt;
    float* sh  = Ut;

    const int tid = threadIdx.x;
    const int rg  = tid >> 5;
    const int cg  = tid & 31;
    const int rr0 = rg * 2;
    const int c0  = cg * 12;
    const size_t row0 = (size_t)blockIdx.x * 16;

    float b0r[12];
#pragma unroll
    for (int j = 0; j < 12; ++j) b0r[j] = bp[c0 + j];

    for (int i = tid; i < 16 * 32; i += 256) h4[i] = make_float4(0, 0, 0, 0);

    for (int t = 0; t < Tt; ++t) {
        __syncthreads();
        for (int i = tid; i < 16 * 32; i += 256) {
            int r = i >> 5, q = i & 31;
            x4[i] = *(const float4*)&hs[((row0 + r) * Tt + t) * Uu + q * 4];
        }
        if (tid < 16) at_l[tid] = ats[(row0 + tid) * Tt + t];

        float4 accx[2][3], acch[2][3];
#pragma unroll
        for (int i = 0; i < 2; ++i)
#pragma unroll
            for (int q = 0; q < 3; ++q) { accx[i][q] = make_float4(0,0,0,0); acch[i][q] = make_float4(0,0,0,0); }

        for (int kt = 0; kt < 4; ++kt) {
            __syncthreads();
            for (int i = tid; i < 32 * 96; i += 256) {
                Wt4[i] = *((const float4*)(Wp + kt * 32 * GN) + i);
                Ut4[i] = *((const float4*)(Up + kt * 32 * GN) + i);
            }
            __syncthreads();
#pragma unroll 4
            for (int k = 0; k < 32; ++k) {
                const int kk = kt * 32 + k;
                float ax0 = x_l[rr0 * 128 + kk];
                float ax1 = x_l[(rr0 + 1) * 128 + kk];
                float ah0 = h_l[rr0 * 128 + kk];
                float ah1 = h_l[(rr0 + 1) * 128 + kk];
                float4 w0 = *(const float4*)&Wt[k * GN + c0];
                float4 w1 = *(const float4*)&Wt[k * GN + c0 + 4];
                float4 w2 = *(const float4*)&Wt[k * GN + c0 + 8];
                float4 u0 = *(const float4*)&Ut[k * GN + c0];
                float4 u1 = *(const float4*)&Ut[k * GN + c0 + 4];
                float4 u2 = *(const float4*)&Ut[k * GN + c0 + 8];
                fma4(accx[0][0], ax0, w0); fma4(accx[0][1], ax0, w1); fma4(accx[0][2], ax0, w2);
                fma4(accx[1][0], ax1, w0); fma4(accx[1][1], ax1, w1); fma4(accx[1][2], ax1, w2);
                fma4(acch[0][0], ah0, u0); fma4(acch[0][1], ah0, u1); fma4(acch[0][2], ah0, u2);
                fma4(acch[1][0], ah1, u0); fma4(acch[1][1], ah1, u1); fma4(acch[1][2], ah1, u2);
            }
        }
        __syncthreads();
#pragma unroll
        for (int i = 0; i < 2; ++i) {
#pragma unroll
            for (int q = 0; q < 3; ++q) {
                float4 vx = accx[i][q];
                vx.x += b0r[q*4+0]; vx.y += b0r[q*4+1]; vx.z += b0r[q*4+2]; vx.w += b0r[q*4+3];
                *(float4*)&sx[(rr0 + i) * GN + c0 + q * 4] = vx;
                *(float4*)&sh[(rr0 + i) * GN + c0 + q * 4] = acch[i][q];
            }
        }
        __syncthreads();
        for (int i = tid; i < 16 * 128; i += 256) {
            int r = i >> 7, u = i & 127;
            float ug = sigf(sx[r * GN + u]       + sh[r * GN + u]);
            float rga= sigf(sx[r * GN + 128 + u] + sh[r * GN + 128 + u]);
            float cg_ = tanhf(sx[r * GN + 256 + u] + rga * sh[r * GN + 256 + u]);
            float uu_ = at_l[r] * ug;
            float hprev = h_l[r * 128 + u];
            h_l[r * 128 + u] = (1.0f - uu_) * hprev + uu_ * cg_;
        }
    }
    __syncthreads();
    for (int i = tid; i < 16 * 128; i += 256) {
        int r = i >> 7, u = i & 127;
        hf[(row0 + r) * Uu + u] = h_l[r * 128 + u];
    }
}

// ---------------- final: BN + 256->256->128->1 ----------------
__global__ __launch_bounds__(256) void final_mlp(
    const float* __restrict__ hf, const float* __restrict__ inputs,
    const float* __restrict__ g, const float* __restrict__ be,
    const float* __restrict__ mu, const float* __restrict__ var,
    const float* __restrict__ W1, const float* __restrict__ b1,
    const float* __restrict__ W2, const float* __restrict__ b2,
    const float* __restrict__ fW, const float* __restrict__ fb,
    float* __restrict__ out)
{
    __shared__ float4 A4[32 * 64];     // xn [32][256]; later d2 [32][132]
    __shared__ float4 Wt4[64 * 64];    // W tiles
    __shared__ float4 B4[32 * 64];     // d1 [32][256]
    __shared__ float  wfl[128];
    float* A = (float*)A4; float* Wt = (float*)Wt4; float* Bb = (float*)B4;

    const int tid = threadIdx.x;
    const size_t r0 = (size_t)blockIdx.x * 32;
    const int rg = tid >> 5, cg = tid & 31;

    for (int i = tid; i < 32 * 256; i += 256) {
        int r = i >> 8, c = i & 255;
        size_t row = r0 + r;
        float v = (c < 128) ? hf[row * 128 + c]
                            : inputs[(row * (Tt + 1) + Tt) * Dd + (c - 128)];
        float xn = (v - mu[c]) / sqrtf(var[c] + 0.001f) * g[c] + be[c];
        A[r * 256 + c] = xn;
    }
    if (tid < 128) wfl[tid] = fW[tid];

    float4 acc[4][2];
#pragma unroll
    for (int i = 0; i < 4; ++i) { acc[i][0] = make_float4(0,0,0,0); acc[i][1] = make_float4(0,0,0,0); }
    float b1r[8];
#pragma unroll
    for (int j = 0; j < 8; ++j) b1r[j] = b1[cg * 8 + j];

    for (int kt = 0; kt < 4; ++kt) {
        __syncthreads();
        for (int i = tid; i < 64 * 64; i += 256)
            Wt4[i] = *((const float4*)(W1 + kt * 64 * 256) + i);
        __syncthreads();
#pragma unroll 2
        for (int k = 0; k < 64; ++k) {
            float4 w0 = *(const float4*)&Wt[k * 256 + cg * 8];
            float4 w1 = *(const float4*)&Wt[k * 256 + cg * 8 + 4];
#pragma unroll
            for (int i = 0; i < 4; ++i) {
                float a = A[(rg * 4 + i) * 256 + kt * 64 + k];
                fma4(acc[i][0], a, w0);
                fma4(acc[i][1], a, w1);
            }
        }
    }
    __syncthreads();
#pragma unroll
    for (int i = 0; i < 4; ++i) {
        float4 v0 = acc[i][0], v1 = acc[i][1];
        v0.x = lky(v0.x + b1r[0]); v0.y = lky(v0.y + b1r[1]); v0.z = lky(v0.z + b1r[2]); v0.w = lky(v0.w + b1r[3]);
        v1.x = lky(v1.x + b1r[4]); v1.y = lky(v1.y + b1r[5]); v1.z = lky(v1.z + b1r[6]); v1.w = lky(v1.w + b1r[7]);
        *(float4*)&Bb[(rg * 4 + i) * 256 + cg * 8]     = v0;
        *(float4*)&Bb[(rg * 4 + i) * 256 + cg * 8 + 4] = v1;
    }

    float4 acc2[4];
#pragma unroll
    for (int i = 0; i < 4; ++i) acc2[i] = make_float4(0,0,0,0);
    float b2r[4];
#pragma unroll
    for (int j = 0; j < 4; ++j) b2r[j] = b2[cg * 4 + j];

    for (int kt = 0; kt < 4; ++kt) {
        __syncthreads();
        for (int i = tid; i < 64 * 32; i += 256)
            Wt4[i] = *((const float4*)(W2 + kt * 64 * 128) + i);
        __syncthreads();
#pragma unroll 2
        for (int k = 0; k < 64; ++k) {
            float4 w = *(const float4*)&Wt[k * 128 + cg * 4];
#pragma unroll
            for (int i = 0; i < 4; ++i) {
                float a = Bb[(rg * 4 + i) * 256 + kt * 64 + k];
                fma4(acc2[i], a, w);
            }
        }
    }
    __syncthreads();  // A no longer read; reuse as d2 [32][132]
#pragma unroll
    for (int i = 0; i < 4; ++i) {
        float4 v = acc2[i];
        v.x = lky(v.x + b2r[0]); v.y = lky(v.y + b2r[1]); v.z = lky(v.z + b2r[2]); v.w = lky(v.w + b2r[3]);
        *(float4*)&A[(rg * 4 + i) * 132 + cg * 4] = v;
    }
    __syncthreads();
    if (tid < 32) {
        float s = fb[0];
#pragma unroll 8
        for (int k = 0; k < 128; ++k) s += A[tid * 132 + k] * wfl[k];
        out[r0 + tid] = sigf(s);
    }
}

extern "C" void kernel_launch(void* const* d_in, const int* in_sizes, int n_in,
                              void* d_out, int out_size, void* d_ws, size_t ws_size,
                              hipStream_t stream)
{
    const float* inputs   = (const float*)d_in[0];
    const float* gru_W    = (const float*)d_in[1];
    const float* gru_U    = (const float*)d_in[2];
    const float* gru_b    = (const float*)d_in[3];
    const float* att_W1   = (const float*)d_in[4];
    const float* att_b1   = (const float*)d_in[5];
    const float* att_W2   = (const float*)d_in[6];
    const float* att_b2   = (const float*)d_in[7];
    const float* att_W3   = (const float*)d_in[8];
    const float* att_b3   = (const float*)d_in[9];
    const float* au_Wu    = (const float*)d_in[10];
    const float* au_bu    = (const float*)d_in[11];
    const float* au_Uu    = (const float*)d_in[12];
    const float* au_Wr    = (const float*)d_in[13];
    const float* au_br    = (const float*)d_in[14];
    const float* au_Ur    = (const float*)d_in[15];
    const float* au_Wc    = (const float*)d_in[16];
    const float* au_bc    = (const float*)d_in[17];
    const float* au_Uc    = (const float*)d_in[18];
    const float* bn_gamma = (const float*)d_in[19];
    const float* bn_beta  = (const float*)d_in[20];
    const float* bn_mean  = (const float*)d_in[21];
    const float* bn_var   = (const float*)d_in[22];
    const float* d_W1     = (const float*)d_in[23];
    const float* d_b1     = (const float*)d_in[24];
    const float* d_W2     = (const float*)d_in[25];
    const float* d_b2     = (const float*)d_in[26];
    const float* f_W      = (const float*)d_in[27];
    const float* f_b      = (const float*)d_in[28];

    float* ws  = (float*)d_ws;
    float* hs  = ws;
    float* ats = hs  + (size_t)Bsz * Tt * Uu;
    float* hf  = ats + (size_t)Bsz * Tt;
    float* Wp  = hf  + (size_t)Bsz * Uu;
    float* Up  = Wp  + (size_t)Uu * GN;
    float* bp  = Up  + (size_t)Uu * GN;

    pack_augru<<<(Uu * GN + 255) / 256, 256, 0, stream>>>(
        au_Wu, au_Wr, au_Wc, au_Uu, au_Ur, au_Uc, au_bu, au_br, au_bc, Wp, Up, bp);
    gru_fused<<<Bsz / 16, 256, 0, stream>>>(inputs, gru_W, gru_U, gru_b, hs);
    attn_kernel<<<Bsz * Tt / 32, 256, 0, stream>>>(
        hs, inputs, att_W1, att_b1, att_W2, att_b2, att_W3, att_b3, ats);
    augru_fused<<<Bsz / 16, 256, 0, stream>>>(hs, Wp, Up, bp, ats, hf);
    final_mlp<<<Bsz / 32, 256, 0, stream>>>(
        hf, inputs, bn_gamma, bn_beta, bn_mean, bn_var,
        d_W1, d_b1, d_W2, d_b2, f_W, f_b, (float*)d_out);
}

// Round 3
// 333.762 us; speedup vs baseline: 9.8087x; 9.8087x over previous
//
#include <hip/hip_runtime.h>
#include <math.h>

// DIEN bf16-MFMA version. B=4096, T=50, D=U=128.
// ws layout (bytes):
//  hs_bf16   52,428,800  @ 0
//  ats_f32      819,200  @ 52,428,800
//  hf_f32     2,097,152  @ 53,248,000
//  Wg_t          98,304  @ 55,345,152   [384][128] bf16 (gru_W^T)
//  Ug_t          98,304  @ 55,443,456
//  Wau_t         98,304  @ 55,541,760
//  Uau_t         98,304  @ 55,640,064
//  AW1_t        131,072  @ 55,738,368   [128][512]
//  AW2_t         16,384  @ 55,869,440   [64][128]
//  DW1_t        131,072  @ 55,885,824   [256][256]
//  DW2_t         65,536  @ 56,016,896   [128][256]
//  bp             1,536  @ 56,082,432   [384] f32
// total ~56.1 MB

#define LK 0.0003f

typedef __attribute__((ext_vector_type(8))) short short8;
typedef __attribute__((ext_vector_type(4))) float f32x4;

union U8 { short8 s; unsigned short u[8]; };

__device__ __forceinline__ float sigf(float x) { return 1.0f / (1.0f + expf(-x)); }
__device__ __forceinline__ float lky(float v) { return v >= 0.0f ? v : LK * v; }
__device__ __forceinline__ unsigned short f2bf(float f) {
    unsigned u = __float_as_uint(f);
    return (unsigned short)((u + 0x7FFFu + ((u >> 16) & 1u)) >> 16);
}
__device__ __forceinline__ float bf2f(unsigned short h) {
    return __uint_as_float(((unsigned)h) << 16);
}
// XOR swizzle: 16B-slot permute within 8-row stripes -> <=2-way bank aliasing (free)
__device__ __forceinline__ int swz(int row, int kbyte, int stride) {
    return row * stride + (kbyte ^ ((row & 7) << 4));
}
__device__ __forceinline__ f32x4 mfma16(short8 a, short8 b, f32x4 c) {
    return __builtin_amdgcn_mfma_f32_16x16x32_bf16(a, b, c, 0, 0, 0);
}

// ---------------- pack & transpose all weights to bf16 [n][k] panels ----------------
__global__ void pack_all(
    const float* __restrict__ gW, const float* __restrict__ gU,
    const float* __restrict__ aWu, const float* __restrict__ aWr, const float* __restrict__ aWc,
    const float* __restrict__ aUu, const float* __restrict__ aUr, const float* __restrict__ aUc,
    const float* __restrict__ tW1, const float* __restrict__ tW2,
    const float* __restrict__ dW1, const float* __restrict__ dW2,
    const float* __restrict__ abu, const float* __restrict__ abr, const float* __restrict__ abc,
    unsigned short* __restrict__ Wg, unsigned short* __restrict__ Ug,
    unsigned short* __restrict__ Wau, unsigned short* __restrict__ Uau,
    unsigned short* __restrict__ AW1, unsigned short* __restrict__ AW2,
    unsigned short* __restrict__ DW1, unsigned short* __restrict__ DW2,
    float* __restrict__ bp)
{
    int i = blockIdx.x * 256 + threadIdx.x;
    if (i < 49152) {                                  // Wg/Ug: [n<384][k<128]
        int n = i >> 7, k = i & 127;
        Wg[i] = f2bf(gW[k * 384 + n]);
        Ug[i] = f2bf(gU[k * 384 + n]);
    } else if (i < 98304) {                           // Wau/Uau
        int j = i - 49152; int n = j >> 7, k = j & 127;
        int g = n >> 7, c = n & 127;
        const float* s = (g == 0) ? aWu : (g == 1) ? aWr : aWc;
        const float* u = (g == 0) ? aUu : (g == 1) ? aUr : aUc;
        Wau[j] = f2bf(s[k * 128 + c]);
        Uau[j] = f2bf(u[k * 128 + c]);
    } else if (i < 163840) {                          // AW1: [n<128][k<512]
        int j = i - 98304; int n = j >> 9, k = j & 511;
        AW1[j] = f2bf(tW1[k * 128 + n]);
    } else if (i < 172032) {                          // AW2: [n<64][k<128]
        int j = i - 163840; int n = j >> 7, k = j & 127;
        AW2[j] = f2bf(tW2[k * 64 + n]);
    } else if (i < 237568) {                          // DW1: [n<256][k<256]
        int j = i - 172032; int n = j >> 8, k = j & 255;
        DW1[j] = f2bf(dW1[k * 256 + n]);
    } else if (i < 270336) {                          // DW2: [n<128][k<256]
        int j = i - 237568; int n = j >> 8, k = j & 255;
        DW2[j] = f2bf(dW2[k * 128 + n]);
    } else if (i < 270720) {
        int j = i - 270336;
        bp[j] = (j < 128) ? abu[j] : (j < 256) ? abr[j - 128] : abc[j - 256];
    }
}

// ---------------- GRU: MFMA recurrence, weights in registers ----------------
// 512 threads = 8 waves; wave w owns output cols [16w,16w+16) of each gate.
__global__ __launch_bounds__(512, 2) void gru_mfma(
    const float* __restrict__ inputs, const unsigned short* __restrict__ Wt,
    const unsigned short* __restrict__ Ut, const float* __restrict__ gb,
    unsigned short* __restrict__ hs)
{
    __shared__ __align__(16) unsigned char xbuf[4096];   // x_t bf16 [16][128] swz
    __shared__ __align__(16) unsigned char hbuf[4096];   // h   bf16 [16][128] swz

    const int tid = threadIdx.x;
    const int wv = tid >> 6, l = tid & 63, l15 = l & 15, lg = l >> 4;
    const size_t row0 = (size_t)blockIdx.x * 16;
    const int ucol = wv * 16 + l15;

    short8 wf[3][4], uf[3][4];
#pragma unroll
    for (int g = 0; g < 3; ++g)
#pragma unroll
        for (int kt = 0; kt < 4; ++kt) {
            int n = g * 128 + ucol;
            int k0 = kt * 32 + lg * 8;
            wf[g][kt] = *(const short8*)(Wt + n * 128 + k0);
            uf[g][kt] = *(const short8*)(Ut + n * 128 + k0);
        }
    const float bx0 = gb[ucol],       bx1 = gb[128 + ucol], bx2 = gb[256 + ucol];
    const float bh0 = gb[384 + ucol], bh1 = gb[512 + ucol], bh2 = gb[640 + ucol];

    const int sr = tid >> 5, ss = tid & 31;   // staging: row 0..15, 4-elem chunk 0..31

    *(uint2*)(hbuf + tid * 8) = make_uint2(0u, 0u);
    {
        float4 v = *(const float4*)&inputs[((row0 + sr) * 51) * 128 + ss * 4];
        unsigned a = (unsigned)f2bf(v.x) | ((unsigned)f2bf(v.y) << 16);
        unsigned b = (unsigned)f2bf(v.z) | ((unsigned)f2bf(v.w) << 16);
        *(uint2*)(xbuf + swz(sr, ss * 8, 256)) = make_uint2(a, b);
    }
    float hreg[4] = {0.f, 0.f, 0.f, 0.f};
    __syncthreads();

    for (int t = 0; t < 50; ++t) {
        float4 xpf;
        if (t < 49) xpf = *(const float4*)&inputs[((row0 + sr) * 51 + (t + 1)) * 128 + ss * 4];

        short8 ax[4], ah[4];
#pragma unroll
        for (int kt = 0; kt < 4; ++kt) {
            int off = swz(l15, kt * 64 + lg * 16, 256);
            ax[kt] = *(const short8*)(xbuf + off);
            ah[kt] = *(const short8*)(hbuf + off);
        }
        f32x4 accx[3], acch[3];
#pragma unroll
        for (int g = 0; g < 3; ++g) {
            accx[g] = (f32x4){0.f, 0.f, 0.f, 0.f};
            acch[g] = (f32x4){0.f, 0.f, 0.f, 0.f};
        }
#pragma unroll
        for (int kt = 0; kt < 4; ++kt)
#pragma unroll
            for (int g = 0; g < 3; ++g) {
                accx[g] = mfma16(ax[kt], wf[g][kt], accx[g]);
                acch[g] = mfma16(ah[kt], uf[g][kt], acch[g]);
            }
        __syncthreads();
#pragma unroll
        for (int j = 0; j < 4; ++j) {
            int m = lg * 4 + j;
            float z  = sigf(accx[0][j] + acch[0][j] + bx0 + bh0);
            float r  = sigf(accx[1][j] + acch[1][j] + bx1 + bh1);
            float hc = tanhf(accx[2][j] + bx2 + r * (acch[2][j] + bh2));
            float hn = z * hreg[j] + (1.f - z) * hc;
            hreg[j] = hn;
            unsigned short hb = f2bf(hn);
            *(unsigned short*)(hbuf + swz(m, ucol * 2, 256)) = hb;
            hs[((row0 + m) * 50 + t) * 128 + ucol] = hb;
        }
        if (t < 49) {
            unsigned a = (unsigned)f2bf(xpf.x) | ((unsigned)f2bf(xpf.y) << 16);
            unsigned b = (unsigned)f2bf(xpf.z) | ((unsigned)f2bf(xpf.w) << 16);
            *(uint2*)(xbuf + swz(sr, ss * 8, 256)) = make_uint2(a, b);
        }
        __syncthreads();
    }
}

// ---------------- attention MLP: fused 512->128->64->1, MFMA ----------------
// 256 threads = 4 waves; 32 rows/block. Wave w: L1 cols [32w,32w+32), L2 cols [16w,16w+16).
__global__ __launch_bounds__(256, 2) void attn_mfma(
    const unsigned short* __restrict__ hsrc, const float* __restrict__ inputs,
    const unsigned short* __restrict__ W1t, const float* __restrict__ b1,
    const unsigned short* __restrict__ W2t, const float* __restrict__ b2,
    const float* __restrict__ W3, const float* __restrict__ b3,
    float* __restrict__ ats)
{
    __shared__ __align__(16) unsigned char emb[32 * 1024];  // [32][512] bf16 swz
    __shared__ __align__(16) unsigned char a1b[32 * 256];   // [32][128] bf16 swz
    __shared__ float a2b[32 * 68];
    __shared__ float w3l[64];

    const int tid = threadIdx.x;
    const int wv = tid >> 6, l = tid & 63, l15 = l & 15, lg = l >> 4;
    const size_t r0 = (size_t)blockIdx.x * 32;

    short8 w1f[2][16];
#pragma unroll
    for (int p = 0; p < 2; ++p)
#pragma unroll
        for (int kt = 0; kt < 16; ++kt) {
            int n = wv * 32 + p * 16 + l15;
            w1f[p][kt] = *(const short8*)(W1t + n * 512 + kt * 32 + lg * 8);
        }
    short8 w2f[4];
#pragma unroll
    for (int kt = 0; kt < 4; ++kt)
        w2f[kt] = *(const short8*)(W2t + (wv * 16 + l15) * 128 + kt * 32 + lg * 8);
    if (tid < 64) w3l[tid] = W3[tid];

    {   // emb staging: thread -> row r=tid>>3, 16-col chunk c=tid&7
        int r = tid >> 3, c = tid & 7, k0 = c * 16;
        size_t row = r0 + r;
        size_t nb = row / 50;
        const float* np = inputs + (nb * 51 + 50) * 128 + k0;
        U8 h0, h1;
        h0.s = *(const short8*)(hsrc + row * 128 + k0);
        h1.s = *(const short8*)(hsrc + row * 128 + k0 + 8);
        float nf[16];
#pragma unroll
        for (int q = 0; q < 16; ++q) nf[q] = np[q];
        U8 d0, d1, e0, e1, p0, p1;
#pragma unroll
        for (int q = 0; q < 8; ++q) {
            float hv0 = bf2f(h0.u[q]), hv1 = bf2f(h1.u[q]);
            d0.u[q] = f2bf(nf[q] - hv0);     d1.u[q] = f2bf(nf[8 + q] - hv1);
            e0.u[q] = f2bf(nf[q]);           e1.u[q] = f2bf(nf[8 + q]);
            p0.u[q] = f2bf(hv0 * nf[q]);     p1.u[q] = f2bf(hv1 * nf[8 + q]);
        }
        *(short8*)(emb + swz(r, k0 * 2, 1024))        = h0.s;
        *(short8*)(emb + swz(r, k0 * 2 + 16, 1024))   = h1.s;
        *(short8*)(emb + swz(r, 256 + k0 * 2, 1024))  = d0.s;
        *(short8*)(emb + swz(r, 256 + k0 * 2 + 16, 1024)) = d1.s;
        *(short8*)(emb + swz(r, 512 + k0 * 2, 1024))  = e0.s;
        *(short8*)(emb + swz(r, 512 + k0 * 2 + 16, 1024)) = e1.s;
        *(short8*)(emb + swz(r, 768 + k0 * 2, 1024))  = p0.s;
        *(short8*)(emb + swz(r, 768 + k0 * 2 + 16, 1024)) = p1.s;
    }
    __syncthreads();

    // L1: [32 rows] x [512] @ [512][128]
    f32x4 acc[2][2];
#pragma unroll
    for (int p = 0; p < 2; ++p)
#pragma unroll
        for (int rt = 0; rt < 2; ++rt) acc[p][rt] = (f32x4){0.f, 0.f, 0.f, 0.f};
#pragma unroll
    for (int rt = 0; rt < 2; ++rt)
#pragma unroll
        for (int kt = 0; kt < 16; ++kt) {
            short8 axx = *(const short8*)(emb + swz(rt * 16 + l15, kt * 64 + lg * 16, 1024));
            acc[0][rt] = mfma16(axx, w1f[0][kt], acc[0][rt]);
            acc[1][rt] = mfma16(axx, w1f[1][kt], acc[1][rt]);
        }
#pragma unroll
    for (int p = 0; p < 2; ++p) {
        float bb = b1[wv * 32 + p * 16 + l15];
#pragma unroll
        for (int rt = 0; rt < 2; ++rt)
#pragma unroll
            for (int j = 0; j < 4; ++j) {
                float v = fmaxf(acc[p][rt][j] + bb, 0.f);
                *(unsigned short*)(a1b + swz(rt * 16 + lg * 4 + j,
                                             (wv * 32 + p * 16 + l15) * 2, 256)) = f2bf(v);
            }
    }
    __syncthreads();

    // L2: [32][128] @ [128][64]
    f32x4 acc2[2];
#pragma unroll
    for (int rt = 0; rt < 2; ++rt) acc2[rt] = (f32x4){0.f, 0.f, 0.f, 0.f};
#pragma unroll
    for (int rt = 0; rt < 2; ++rt)
#pragma unroll
        for (int kt = 0; kt < 4; ++kt) {
            short8 axx = *(const short8*)(a1b + swz(rt * 16 + l15, kt * 64 + lg * 16, 256));
            acc2[rt] = mfma16(axx, w2f[kt], acc2[rt]);
        }
    {
        float bb = b2[wv * 16 + l15];
#pragma unroll
        for (int rt = 0; rt < 2; ++rt)
#pragma unroll
            for (int j = 0; j < 4; ++j)
                a2b[(rt * 16 + lg * 4 + j) * 68 + wv * 16 + l15] = fmaxf(acc2[rt][j] + bb, 0.f);
    }
    __syncthreads();

    if (tid < 32) {
        float s = b3[0];
#pragma unroll 8
        for (int k = 0; k < 64; ++k) s += a2b[tid * 68 + k] * w3l[k];
        ats[r0 + tid] = sigf(s);
    }
}

// ---------------- AUGRU: MFMA recurrence with attention gate ----------------
__global__ __launch_bounds__(512, 2) void augru_mfma(
    const unsigned short* __restrict__ hsrc, const unsigned short* __restrict__ Wt,
    const unsigned short* __restrict__ Ut, const float* __restrict__ bp,
    const float* __restrict__ ats, float* __restrict__ hf)
{
    __shared__ __align__(16) unsigned char xbuf[4096];
    __shared__ __align__(16) unsigned char hbuf[4096];

    const int tid = threadIdx.x;
    const int wv = tid >> 6, l = tid & 63, l15 = l & 15, lg = l >> 4;
    const size_t row0 = (size_t)blockIdx.x * 16;
    const int ucol = wv * 16 + l15;

    short8 wf[3][4], uf[3][4];
#pragma unroll
    for (int g = 0; g < 3; ++g)
#pragma unroll
        for (int kt = 0; kt < 4; ++kt) {
            int n = g * 128 + ucol;
            int k0 = kt * 32 + lg * 8;
            wf[g][kt] = *(const short8*)(Wt + n * 128 + k0);
            uf[g][kt] = *(const short8*)(Ut + n * 128 + k0);
        }
    const float bx0 = bp[ucol], bx1 = bp[128 + ucol], bx2 = bp[256 + ucol];

    const int sr = tid >> 5, ss = tid & 31;

    *(uint2*)(hbuf + tid * 8) = make_uint2(0u, 0u);
    {
        uint2 v = *(const uint2*)(hsrc + ((row0 + sr) * 50) * 128 + ss * 4);
        *(uint2*)(xbuf + swz(sr, ss * 8, 256)) = v;
    }
    float hreg[4] = {0.f, 0.f, 0.f, 0.f};
    __syncthreads();

    for (int t = 0; t < 50; ++t) {
        uint2 xpf;
        if (t < 49) xpf = *(const uint2*)(hsrc + ((row0 + sr) * 50 + t + 1) * 128 + ss * 4);
        float at4[4];
#pragma unroll
        for (int j = 0; j < 4; ++j) at4[j] = ats[(row0 + lg * 4 + j) * 50 + t];

        short8 ax[4], ah[4];
#pragma unroll
        for (int kt = 0; kt < 4; ++kt) {
            int off = swz(l15, kt * 64 + lg * 16, 256);
            ax[kt] = *(const short8*)(xbuf + off);
            ah[kt] = *(const short8*)(hbuf + off);
        }
        f32x4 accx[3], acch[3];
#pragma unroll
        for (int g = 0; g < 3; ++g) {
            accx[g] = (f32x4){0.f, 0.f, 0.f, 0.f};
            acch[g] = (f32x4){0.f, 0.f, 0.f, 0.f};
        }
#pragma unroll
        for (int kt = 0; kt < 4; ++kt)
#pragma unroll
            for (int g = 0; g < 3; ++g) {
                accx[g] = mfma16(ax[kt], wf[g][kt], accx[g]);
                acch[g] = mfma16(ah[kt], uf[g][kt], acch[g]);
            }
        __syncthreads();
#pragma unroll
        for (int j = 0; j < 4; ++j) {
            int m = lg * 4 + j;
            float u  = sigf(accx[0][j] + bx0 + acch[0][j]);
            float r  = sigf(accx[1][j] + bx1 + acch[1][j]);
            float c  = tanhf(accx[2][j] + bx2 + r * acch[2][j]);
            float uu = at4[j] * u;
            float hn = (1.f - uu) * hreg[j] + uu * c;
            hreg[j] = hn;
            *(unsigned short*)(hbuf + swz(m, ucol * 2, 256)) = f2bf(hn);
        }
        if (t < 49) *(uint2*)(xbuf + swz(sr, ss * 8, 256)) = xpf;
        __syncthreads();
    }
#pragma unroll
    for (int j = 0; j < 4; ++j)
        hf[(row0 + lg * 4 + j) * 128 + ucol] = hreg[j];
}

// ---------------- final: BN + 256->256->128->1, MFMA ----------------
__global__ __launch_bounds__(256, 2) void final_mfma(
    const float* __restrict__ hfv, const float* __restrict__ inputs,
    const float* __restrict__ gam, const float* __restrict__ bet,
    const float* __restrict__ mu, const float* __restrict__ var,
    const unsigned short* __restrict__ W1t, const float* __restrict__ b1,
    const unsigned short* __restrict__ W2t, const float* __restrict__ b2,
    const float* __restrict__ fW, const float* __restrict__ fb,
    float* __restrict__ out)
{
    __shared__ __align__(16) unsigned char xnb[16 * 512];  // [16][256] bf16 swz
    __shared__ __align__(16) unsigned char d1b[16 * 512];  // [16][256] bf16 swz
    __shared__ float d2b[16 * 132];
    __shared__ float wfl[128];

    const int tid = threadIdx.x;
    const int wv = tid >> 6, l = tid & 63, l15 = l & 15, lg = l >> 4;
    const size_t r0 = (size_t)blockIdx.x * 16;

    short8 w1f[4][8];
#pragma unroll
    for (int p = 0; p < 4; ++p)
#pragma unroll
        for (int kt = 0; kt < 8; ++kt) {
            int n = wv * 64 + p * 16 + l15;
            w1f[p][kt] = *(const short8*)(W1t + n * 256 + kt * 32 + lg * 8);
        }
    short8 w2f[2][8];
#pragma unroll
    for (int p = 0; p < 2; ++p)
#pragma unroll
        for (int kt = 0; kt < 8; ++kt) {
            int n = wv * 32 + p * 16 + l15;
            w2f[p][kt] = *(const short8*)(W2t + n * 256 + kt * 32 + lg * 8);
        }
    if (tid < 128) wfl[tid] = fW[tid];

    {   // stage BN-normalized input, bf16 swz
        int r = tid >> 4, c = tid & 15, k0 = c * 16;
        float v[16];
#pragma unroll
        for (int q = 0; q < 16; ++q) {
            int k = k0 + q;
            float x = (k < 128) ? hfv[(r0 + r) * 128 + k]
                                : inputs[((r0 + r) * 51 + 50) * 128 + (k - 128)];
            float s = gam[k] * rsqrtf(var[k] + 0.001f);
            v[q] = (x - mu[k]) * s + bet[k];
        }
        U8 t0, t1;
#pragma unroll
        for (int q = 0; q < 8; ++q) { t0.u[q] = f2bf(v[q]); t1.u[q] = f2bf(v[8 + q]); }
        *(short8*)(xnb + swz(r, k0 * 2, 512))      = t0.s;
        *(short8*)(xnb + swz(r, k0 * 2 + 16, 512)) = t1.s;
    }
    __syncthreads();

    // L1: [16][256] @ [256][256], leaky
    f32x4 a1[4];
#pragma unroll
    for (int p = 0; p < 4; ++p) a1[p] = (f32x4){0.f, 0.f, 0.f, 0.f};
#pragma unroll
    for (int kt = 0; kt < 8; ++kt) {
        short8 axx = *(const short8*)(xnb + swz(l15, kt * 64 + lg * 16, 512));
#pragma unroll
        for (int p = 0; p < 4; ++p) a1[p] = mfma16(axx, w1f[p][kt], a1[p]);
    }
#pragma unroll
    for (int p = 0; p < 4; ++p) {
        float bb = b1[wv * 64 + p * 16 + l15];
#pragma unroll
        for (int j = 0; j < 4; ++j) {
            int row = lg * 4 + j, col = wv * 64 + p * 16 + l15;
            *(unsigned short*)(d1b + swz(row, col * 2, 512)) = f2bf(lky(a1[p][j] + bb));
        }
    }
    __syncthreads();

    // L2: [16][256] @ [256][128], leaky
    f32x4 a2[2];
#pragma unroll
    for (int p = 0; p < 2; ++p) a2[p] = (f32x4){0.f, 0.f, 0.f, 0.f};
#pragma unroll
    for (int kt = 0; kt < 8; ++kt) {
        short8 axx = *(const short8*)(d1b + swz(l15, kt * 64 + lg * 16, 512));
#pragma unroll
        for (int p = 0; p < 2; ++p) a2[p] = mfma16(axx, w2f[p][kt], a2[p]);
    }
#pragma unroll
    for (int p = 0; p < 2; ++p) {
        float bb = b2[wv * 32 + p * 16 + l15];
#pragma unroll
        for (int j = 0; j < 4; ++j)
            d2b[(lg * 4 + j) * 132 + wv * 32 + p * 16 + l15] = lky(a2[p][j] + bb);
    }
    __syncthreads();

    if (tid < 16) {
        float s = fb[0];
#pragma unroll 8
        for (int k = 0; k < 128; ++k) s += d2b[tid * 132 + k] * wfl[k];
        out[r0 + tid] = sigf(s);
    }
}

extern "C" void kernel_launch(void* const* d_in, const int* in_sizes, int n_in,
                              void* d_out, int out_size, void* d_ws, size_t ws_size,
                              hipStream_t stream)
{
    const float* inputs   = (const float*)d_in[0];
    const float* gru_W    = (const float*)d_in[1];
    const float* gru_U    = (const float*)d_in[2];
    const float* gru_b    = (const float*)d_in[3];
    const float* att_W1   = (const float*)d_in[4];
    const float* att_b1   = (const float*)d_in[5];
    const float* att_W2   = (const float*)d_in[6];
    const float* att_b2   = (const float*)d_in[7];
    const float* att_W3   = (const float*)d_in[8];
    const float* att_b3   = (const float*)d_in[9];
    const float* au_Wu    = (const float*)d_in[10];
    const float* au_bu    = (const float*)d_in[11];
    const float* au_Uu    = (const float*)d_in[12];
    const float* au_Wr    = (const float*)d_in[13];
    const float* au_br    = (const float*)d_in[14];
    const float* au_Ur    = (const float*)d_in[15];
    const float* au_Wc    = (const float*)d_in[16];
    const float* au_bc    = (const float*)d_in[17];
    const float* au_Uc    = (const float*)d_in[18];
    const float* bn_gamma = (const float*)d_in[19];
    const float* bn_beta  = (const float*)d_in[20];
    const float* bn_mean  = (const float*)d_in[21];
    const float* bn_var   = (const float*)d_in[22];
    const float* d_W1     = (const float*)d_in[23];
    const float* d_b1     = (const float*)d_in[24];
    const float* d_W2     = (const float*)d_in[25];
    const float* d_b2     = (const float*)d_in[26];
    const float* f_W      = (const float*)d_in[27];
    const float* f_b      = (const float*)d_in[28];

    char* w = (char*)d_ws;
    unsigned short* hs  = (unsigned short*)w;
    float* ats          = (float*)(w + 52428800);
    float* hf           = (float*)(w + 53248000);
    unsigned short* Wg  = (unsigned short*)(w + 55345152);
    unsigned short* Ug  = (unsigned short*)(w + 55443456);
    unsigned short* Wau = (unsigned short*)(w + 55541760);
    unsigned short* Uau = (unsigned short*)(w + 55640064);
    unsigned short* AW1 = (unsigned short*)(w + 55738368);
    unsigned short* AW2 = (unsigned short*)(w + 55869440);
    unsigned short* DW1 = (unsigned short*)(w + 55885824);
    unsigned short* DW2 = (unsigned short*)(w + 56016896);
    float* bp           = (float*)(w + 56082432);

    pack_all<<<1058, 256, 0, stream>>>(
        gru_W, gru_U, au_Wu, au_Wr, au_Wc, au_Uu, au_Ur, au_Uc,
        att_W1, att_W2, d_W1, d_W2, au_bu, au_br, au_bc,
        Wg, Ug, Wau, Uau, AW1, AW2, DW1, DW2, bp);
    gru_mfma<<<256, 512, 0, stream>>>(inputs, Wg, Ug, gru_b, hs);
    attn_mfma<<<6400, 256, 0, stream>>>(hs, inputs, AW1, att_b1, AW2, att_b2,
                                        att_W3, att_b3, ats);
    augru_mfma<<<256, 512, 0, stream>>>(hs, Wau, Uau, bp, ats, hf);
    final_mfma<<<256, 256, 0, stream>>>(hf, inputs, bn_gamma, bn_beta, bn_mean, bn_var,
                                        DW1, d_b1, DW2, d_b2, f_W, f_b, (float*)d_out);
}

// Round 4
// 237.330 us; speedup vs baseline: 13.7942x; 1.4063x over previous
//
#include <hip/hip_runtime.h>
#include <math.h>

// DIEN bf16-MFMA v2. B=4096, T=50, D=U=128.
// attn uses algebraic split: emb@W1 = hs@Wa + (hs*news)@Wd + nterm(b),
//   Wa = W1[0:128]-W1[128:256], Wd = W1[384:512], nterm = news@(W1[128:256]+W1[256:384]) + b1.
// ws layout (bytes):
//  hs_bf16    52,428,800 @ 0
//  ats_f32       819,200 @ 52,428,800
//  hf_f32      2,097,152 @ 53,248,000
//  nterm_f32   2,097,152 @ 55,345,152
//  Wg          98,304 @ 57,442,304   [384][128] bf16
//  Ug          98,304 @ 57,540,608
//  Wau         98,304 @ 57,638,912
//  Uau         98,304 @ 57,737,216
//  WA          65,536 @ 57,835,520   [128][256] bf16 (k<128: Wa, k>=128: Wd)
//  WN          32,768 @ 57,901,056   [128][128] bf16
//  AW2         16,384 @ 57,933,824   [64][128] bf16
//  DW1        131,072 @ 57,950,208   [256][256] bf16
//  DW2         65,536 @ 58,081,280   [128][256] bf16
//  bp           1,536 @ 58,146,816   [384] f32
// total 58,148,352 B.

#define LK 0.0003f

typedef __attribute__((ext_vector_type(8))) short short8;
typedef __attribute__((ext_vector_type(4))) float f32x4;

union U8 { short8 s; unsigned short u[8]; };

__device__ __forceinline__ float sigf(float x) { return 1.0f / (1.0f + __expf(-x)); }
__device__ __forceinline__ float tanhfast(float x) { return 2.0f / (1.0f + __expf(-2.0f * x)) - 1.0f; }
__device__ __forceinline__ float lky(float v) { return v >= 0.0f ? v : LK * v; }
__device__ __forceinline__ unsigned short f2bf(float f) {
    unsigned u = __float_as_uint(f);
    return (unsigned short)((u + 0x7FFFu + ((u >> 16) & 1u)) >> 16);
}
__device__ __forceinline__ float bf2f(unsigned short h) {
    return __uint_as_float(((unsigned)h) << 16);
}
// XOR swizzle: 16B-slot permute within 8-row stripes -> <=2-way bank aliasing (free)
__device__ __forceinline__ int swz(int row, int kbyte, int stride) {
    return row * stride + (kbyte ^ ((row & 7) << 4));
}
__device__ __forceinline__ f32x4 mfma16(short8 a, short8 b, f32x4 c) {
    return __builtin_amdgcn_mfma_f32_16x16x32_bf16(a, b, c, 0, 0, 0);
}

// ---------------- pack & transpose all weights to bf16 [n][k] panels ----------------
__global__ void pack_all(
    const float* __restrict__ gW, const float* __restrict__ gU,
    const float* __restrict__ aWu, const float* __restrict__ aWr, const float* __restrict__ aWc,
    const float* __restrict__ aUu, const float* __restrict__ aUr, const float* __restrict__ aUc,
    const float* __restrict__ tW1, const float* __restrict__ tW2,
    const float* __restrict__ dW1, const float* __restrict__ dW2,
    const float* __restrict__ abu, const float* __restrict__ abr, const float* __restrict__ abc,
    unsigned short* __restrict__ Wg, unsigned short* __restrict__ Ug,
    unsigned short* __restrict__ Wau, unsigned short* __restrict__ Uau,
    unsigned short* __restrict__ WA, unsigned short* __restrict__ WN,
    unsigned short* __restrict__ AW2,
    unsigned short* __restrict__ DW1, unsigned short* __restrict__ DW2,
    float* __restrict__ bp)
{
    int i = blockIdx.x * 256 + threadIdx.x;
    if (i < 49152) {                                  // Wg/Ug: [n<384][k<128]
        int n = i >> 7, k = i & 127;
        Wg[i] = f2bf(gW[k * 384 + n]);
        Ug[i] = f2bf(gU[k * 384 + n]);
    } else if (i < 98304) {                           // Wau/Uau
        int j = i - 49152; int n = j >> 7, k = j & 127;
        int g = n >> 7, c = n & 127;
        const float* s = (g == 0) ? aWu : (g == 1) ? aWr : aWc;
        const float* u = (g == 0) ? aUu : (g == 1) ? aUr : aUc;
        Wau[j] = f2bf(s[k * 128 + c]);
        Uau[j] = f2bf(u[k * 128 + c]);
    } else if (i < 131072) {                          // WA: [n<128][k<256]
        int j = i - 98304; int n = j >> 8, k = j & 255;
        float v = (k < 128) ? (tW1[k * 128 + n] - tW1[(128 + k) * 128 + n])
                            : tW1[(384 + (k - 128)) * 128 + n];
        WA[j] = f2bf(v);
    } else if (i < 147456) {                          // WN: [n<128][k<128]
        int j = i - 131072; int n = j >> 7, k = j & 127;
        WN[j] = f2bf(tW1[(128 + k) * 128 + n] + tW1[(256 + k) * 128 + n]);
    } else if (i < 155648) {                          // AW2: [n<64][k<128]
        int j = i - 147456; int n = j >> 7, k = j & 127;
        AW2[j] = f2bf(tW2[k * 64 + n]);
    } else if (i < 221184) {                          // DW1: [n<256][k<256]
        int j = i - 155648; int n = j >> 8, k = j & 255;
        DW1[j] = f2bf(dW1[k * 256 + n]);
    } else if (i < 253952) {                          // DW2: [n<128][k<256]
        int j = i - 221184; int n = j >> 8, k = j & 255;
        DW2[j] = f2bf(dW2[k * 128 + n]);
    } else if (i < 254336) {
        int j = i - 253952;
        bp[j] = (j < 128) ? abu[j] : (j < 256) ? abr[j - 128] : abc[j - 256];
    }
}

// ---------------- nterm = news @ WN + b1  (4096 x 128, K=128) ----------------
__global__ __launch_bounds__(512, 2) void nterm_kernel(
    const float* __restrict__ inputs, const unsigned short* __restrict__ WN,
    const float* __restrict__ b1, float* __restrict__ nterm)
{
    __shared__ __align__(16) unsigned char nb[64 * 256];  // [64][128] bf16 swz

    const int tid = threadIdx.x;
    const int wv = tid >> 6, l = tid & 63, l15 = l & 15, lg = l >> 4;
    const size_t b0 = (size_t)blockIdx.x * 64;

    {
        int r = tid >> 3, c = tid & 7;
        const float* src = inputs + ((b0 + r) * 51 + 50) * 128 + c * 16;
        float4 v0 = *(const float4*)(src);
        float4 v1 = *(const float4*)(src + 4);
        float4 v2 = *(const float4*)(src + 8);
        float4 v3 = *(const float4*)(src + 12);
        U8 t0, t1;
        t0.u[0] = f2bf(v0.x); t0.u[1] = f2bf(v0.y); t0.u[2] = f2bf(v0.z); t0.u[3] = f2bf(v0.w);
        t0.u[4] = f2bf(v1.x); t0.u[5] = f2bf(v1.y); t0.u[6] = f2bf(v1.z); t0.u[7] = f2bf(v1.w);
        t1.u[0] = f2bf(v2.x); t1.u[1] = f2bf(v2.y); t1.u[2] = f2bf(v2.z); t1.u[3] = f2bf(v2.w);
        t1.u[4] = f2bf(v3.x); t1.u[5] = f2bf(v3.y); t1.u[6] = f2bf(v3.z); t1.u[7] = f2bf(v3.w);
        *(short8*)(nb + swz(r, c * 32, 256))      = t0.s;
        *(short8*)(nb + swz(r, c * 32 + 16, 256)) = t1.s;
    }
    __syncthreads();

    short8 wf[4];
#pragma unroll
    for (int kt = 0; kt < 4; ++kt)
        wf[kt] = *(const short8*)(WN + (wv * 16 + l15) * 128 + kt * 32 + lg * 8);

    f32x4 acc[4];
#pragma unroll
    for (int rt = 0; rt < 4; ++rt) acc[rt] = (f32x4){0.f, 0.f, 0.f, 0.f};
#pragma unroll
    for (int rt = 0; rt < 4; ++rt)
#pragma unroll
        for (int kt = 0; kt < 4; ++kt) {
            short8 axx = *(const short8*)(nb + swz(rt * 16 + l15, kt * 64 + lg * 16, 256));
            acc[rt] = mfma16(axx, wf[kt], acc[rt]);
        }
    float bb = b1[wv * 16 + l15];
#pragma unroll
    for (int rt = 0; rt < 4; ++rt)
#pragma unroll
        for (int j = 0; j < 4; ++j)
            nterm[(b0 + rt * 16 + lg * 4 + j) * 128 + wv * 16 + l15] = acc[rt][j] + bb;
}

// ---------------- GRU: MFMA recurrence, weights in registers ----------------
__global__ __launch_bounds__(512, 2) void gru_mfma(
    const float* __restrict__ inputs, const unsigned short* __restrict__ Wt,
    const unsigned short* __restrict__ Ut, const float* __restrict__ gb,
    unsigned short* __restrict__ hs)
{
    __shared__ __align__(16) unsigned char xbuf[4096];   // x_t bf16 [16][128] swz
    __shared__ __align__(16) unsigned char hbuf[4096];   // h   bf16 [16][128] swz

    const int tid = threadIdx.x;
    const int wv = tid >> 6, l = tid & 63, l15 = l & 15, lg = l >> 4;
    const size_t row0 = (size_t)blockIdx.x * 16;
    const int ucol = wv * 16 + l15;

    short8 wf[3][4], uf[3][4];
#pragma unroll
    for (int g = 0; g < 3; ++g)
#pragma unroll
        for (int kt = 0; kt < 4; ++kt) {
            int n = g * 128 + ucol;
            int k0 = kt * 32 + lg * 8;
            wf[g][kt] = *(const short8*)(Wt + n * 128 + k0);
            uf[g][kt] = *(const short8*)(Ut + n * 128 + k0);
        }
    const float bx0 = gb[ucol],       bx1 = gb[128 + ucol], bx2 = gb[256 + ucol];
    const float bh0 = gb[384 + ucol], bh1 = gb[512 + ucol], bh2 = gb[640 + ucol];

    const int sr = tid >> 5, ss = tid & 31;

    *(uint2*)(hbuf + tid * 8) = make_uint2(0u, 0u);
    {
        float4 v = *(const float4*)&inputs[((row0 + sr) * 51) * 128 + ss * 4];
        unsigned a = (unsigned)f2bf(v.x) | ((unsigned)f2bf(v.y) << 16);
        unsigned b = (unsigned)f2bf(v.z) | ((unsigned)f2bf(v.w) << 16);
        *(uint2*)(xbuf + swz(sr, ss * 8, 256)) = make_uint2(a, b);
    }
    float hreg[4] = {0.f, 0.f, 0.f, 0.f};
    __syncthreads();

    for (int t = 0; t < 50; ++t) {
        float4 xpf;
        if (t < 49) xpf = *(const float4*)&inputs[((row0 + sr) * 51 + (t + 1)) * 128 + ss * 4];

        short8 ax[4], ah[4];
#pragma unroll
        for (int kt = 0; kt < 4; ++kt) {
            int off = swz(l15, kt * 64 + lg * 16, 256);
            ax[kt] = *(const short8*)(xbuf + off);
            ah[kt] = *(const short8*)(hbuf + off);
        }
        f32x4 accx[3], acch[3];
#pragma unroll
        for (int g = 0; g < 3; ++g) {
            accx[g] = (f32x4){0.f, 0.f, 0.f, 0.f};
            acch[g] = (f32x4){0.f, 0.f, 0.f, 0.f};
        }
#pragma unroll
        for (int kt = 0; kt < 4; ++kt)
#pragma unroll
            for (int g = 0; g < 3; ++g) {
                accx[g] = mfma16(ax[kt], wf[g][kt], accx[g]);
                acch[g] = mfma16(ah[kt], uf[g][kt], acch[g]);
            }
        __syncthreads();
#pragma unroll
        for (int j = 0; j < 4; ++j) {
            int m = lg * 4 + j;
            float z  = sigf(accx[0][j] + acch[0][j] + bx0 + bh0);
            float r  = sigf(accx[1][j] + acch[1][j] + bx1 + bh1);
            float hc = tanhfast(accx[2][j] + bx2 + r * (acch[2][j] + bh2));
            float hn = z * hreg[j] + (1.f - z) * hc;
            hreg[j] = hn;
            unsigned short hb = f2bf(hn);
            *(unsigned short*)(hbuf + swz(m, ucol * 2, 256)) = hb;
            hs[((row0 + m) * 50 + t) * 128 + ucol] = hb;
        }
        if (t < 49) {
            unsigned a = (unsigned)f2bf(xpf.x) | ((unsigned)f2bf(xpf.y) << 16);
            unsigned b = (unsigned)f2bf(xpf.z) | ((unsigned)f2bf(xpf.w) << 16);
            *(uint2*)(xbuf + swz(sr, ss * 8, 256)) = make_uint2(a, b);
        }
        __syncthreads();
    }
}

// ---------------- attention MLP v2: 64 rows/block, 8 waves ----------------
// a1 = relu(hs@Wa + (hs*news)@Wd + nterm[b]); a2 = relu(a1@W2+b2); ats = sig(a2@W3+b3)
__global__ __launch_bounds__(512, 2) void attn_mfma(
    const unsigned short* __restrict__ hsrc, const float* __restrict__ inputs,
    const float* __restrict__ nterm,
    const unsigned short* __restrict__ WA, const unsigned short* __restrict__ W2t,
    const float* __restrict__ b2, const float* __restrict__ W3,
    const float* __restrict__ b3, float* __restrict__ ats)
{
    __shared__ __align__(16) unsigned char Ab[64 * 512];   // [64][256] bf16 swz (hs | hs*news)
    __shared__ __align__(16) unsigned char a1b[64 * 256];  // [64][128] bf16 swz
    __shared__ float a2b[64 * 65];
    __shared__ float w3l[64];

    const int tid = threadIdx.x;
    const int wv = tid >> 6, l = tid & 63, l15 = l & 15, lg = l >> 4;
    const size_t r0 = (size_t)blockIdx.x * 64;
    const int ncol = wv * 16 + l15;

    short8 waf[8];
#pragma unroll
    for (int kt = 0; kt < 8; ++kt)
        waf[kt] = *(const short8*)(WA + ncol * 256 + kt * 32 + lg * 8);
    short8 w2f[4];
    const int hw = wv >> 2, cq = wv & 3, n2 = cq * 16 + l15;
#pragma unroll
    for (int kt = 0; kt < 4; ++kt)
        w2f[kt] = *(const short8*)(W2t + n2 * 128 + kt * 32 + lg * 8);
    if (tid < 64) w3l[tid] = W3[tid];

    {   // stage A: row r=tid>>3, 16-col chunk c=tid&7
        int r = tid >> 3, c = tid & 7, k0 = c * 16;
        size_t row = r0 + r;
        size_t b = row / 50;
        const float* np = inputs + (b * 51 + 50) * 128 + k0;
        float4 v0 = *(const float4*)(np);
        float4 v1 = *(const float4*)(np + 4);
        float4 v2 = *(const float4*)(np + 8);
        float4 v3 = *(const float4*)(np + 12);
        float nf[16] = {v0.x,v0.y,v0.z,v0.w, v1.x,v1.y,v1.z,v1.w,
                        v2.x,v2.y,v2.z,v2.w, v3.x,v3.y,v3.z,v3.w};
        U8 h0, h1, p0, p1;
        h0.s = *(const short8*)(hsrc + row * 128 + k0);
        h1.s = *(const short8*)(hsrc + row * 128 + k0 + 8);
#pragma unroll
        for (int q = 0; q < 8; ++q) {
            p0.u[q] = f2bf(bf2f(h0.u[q]) * nf[q]);
            p1.u[q] = f2bf(bf2f(h1.u[q]) * nf[8 + q]);
        }
        *(short8*)(Ab + swz(r, k0 * 2, 512))            = h0.s;
        *(short8*)(Ab + swz(r, k0 * 2 + 16, 512))       = h1.s;
        *(short8*)(Ab + swz(r, 256 + k0 * 2, 512))      = p0.s;
        *(short8*)(Ab + swz(r, 256 + k0 * 2 + 16, 512)) = p1.s;
    }
    __syncthreads();

    // L1: [64][256] @ [256][128] + nterm, relu
    f32x4 acc[4];
#pragma unroll
    for (int rt = 0; rt < 4; ++rt) acc[rt] = (f32x4){0.f, 0.f, 0.f, 0.f};
#pragma unroll
    for (int rt = 0; rt < 4; ++rt)
#pragma unroll
        for (int kt = 0; kt < 8; ++kt) {
            short8 axx = *(const short8*)(Ab + swz(rt * 16 + l15, kt * 64 + lg * 16, 512));
            acc[rt] = mfma16(axx, waf[kt], acc[rt]);
        }
#pragma unroll
    for (int rt = 0; rt < 4; ++rt)
#pragma unroll
        for (int j = 0; j < 4; ++j) {
            int row = rt * 16 + lg * 4 + j;
            int b = (int)((r0 + row) / 50);
            float v = fmaxf(acc[rt][j] + nterm[b * 128 + ncol], 0.f);
            *(unsigned short*)(a1b + swz(row, ncol * 2, 256)) = f2bf(v);
        }
    __syncthreads();

    // L2: [64][128] @ [128][64], relu. wave -> (row half hw, col group cq)
    f32x4 acc2[2];
    acc2[0] = (f32x4){0.f, 0.f, 0.f, 0.f};
    acc2[1] = (f32x4){0.f, 0.f, 0.f, 0.f};
#pragma unroll
    for (int rr = 0; rr < 2; ++rr)
#pragma unroll
        for (int kt = 0; kt < 4; ++kt) {
            short8 axx = *(const short8*)(a1b + swz(hw * 32 + rr * 16 + l15, kt * 64 + lg * 16, 256));
            acc2[rr] = mfma16(axx, w2f[kt], acc2[rr]);
        }
    {
        float bb2 = b2[n2];
#pragma unroll
        for (int rr = 0; rr < 2; ++rr)
#pragma unroll
            for (int j = 0; j < 4; ++j)
                a2b[(hw * 32 + rr * 16 + lg * 4 + j) * 65 + n2] = fmaxf(acc2[rr][j] + bb2, 0.f);
    }
    __syncthreads();

    if (tid < 64) {
        float s = b3[0];
#pragma unroll 8
        for (int k = 0; k < 64; ++k) s += a2b[tid * 65 + k] * w3l[k];
        ats[r0 + tid] = sigf(s);
    }
}

// ---------------- AUGRU: MFMA recurrence with attention gate ----------------
__global__ __launch_bounds__(512, 2) void augru_mfma(
    const unsigned short* __restrict__ hsrc, const unsigned short* __restrict__ Wt,
    const unsigned short* __restrict__ Ut, const float* __restrict__ bp,
    const float* __restrict__ ats, float* __restrict__ hf)
{
    __shared__ __align__(16) unsigned char xbuf[4096];
    __shared__ __align__(16) unsigned char hbuf[4096];

    const int tid = threadIdx.x;
    const int wv = tid >> 6, l = tid & 63, l15 = l & 15, lg = l >> 4;
    const size_t row0 = (size_t)blockIdx.x * 16;
    const int ucol = wv * 16 + l15;

    short8 wf[3][4], uf[3][4];
#pragma unroll
    for (int g = 0; g < 3; ++g)
#pragma unroll
        for (int kt = 0; kt < 4; ++kt) {
            int n = g * 128 + ucol;
            int k0 = kt * 32 + lg * 8;
            wf[g][kt] = *(const short8*)(Wt + n * 128 + k0);
            uf[g][kt] = *(const short8*)(Ut + n * 128 + k0);
        }
    const float bx0 = bp[ucol], bx1 = bp[128 + ucol], bx2 = bp[256 + ucol];

    const int sr = tid >> 5, ss = tid & 31;

    *(uint2*)(hbuf + tid * 8) = make_uint2(0u, 0u);
    {
        uint2 v = *(const uint2*)(hsrc + ((row0 + sr) * 50) * 128 + ss * 4);
        *(uint2*)(xbuf + swz(sr, ss * 8, 256)) = v;
    }
    float hreg[4] = {0.f, 0.f, 0.f, 0.f};
    __syncthreads();

    for (int t = 0; t < 50; ++t) {
        uint2 xpf;
        if (t < 49) xpf = *(const uint2*)(hsrc + ((row0 + sr) * 50 + t + 1) * 128 + ss * 4);
        float at4[4];
#pragma unroll
        for (int j = 0; j < 4; ++j) at4[j] = ats[(row0 + lg * 4 + j) * 50 + t];

        short8 ax[4], ah[4];
#pragma unroll
        for (int kt = 0; kt < 4; ++kt) {
            int off = swz(l15, kt * 64 + lg * 16, 256);
            ax[kt] = *(const short8*)(xbuf + off);
            ah[kt] = *(const short8*)(hbuf + off);
        }
        f32x4 accx[3], acch[3];
#pragma unroll
        for (int g = 0; g < 3; ++g) {
            accx[g] = (f32x4){0.f, 0.f, 0.f, 0.f};
            acch[g] = (f32x4){0.f, 0.f, 0.f, 0.f};
        }
#pragma unroll
        for (int kt = 0; kt < 4; ++kt)
#pragma unroll
            for (int g = 0; g < 3; ++g) {
                accx[g] = mfma16(ax[kt], wf[g][kt], accx[g]);
                acch[g] = mfma16(ah[kt], uf[g][kt], acch[g]);
            }
        __syncthreads();
#pragma unroll
        for (int j = 0; j < 4; ++j) {
            int m = lg * 4 + j;
            float u  = sigf(accx[0][j] + bx0 + acch[0][j]);
            float r  = sigf(accx[1][j] + bx1 + acch[1][j]);
            float c  = tanhfast(accx[2][j] + bx2 + r * acch[2][j]);
            float uu = at4[j] * u;
            float hn = (1.f - uu) * hreg[j] + uu * c;
            hreg[j] = hn;
            *(unsigned short*)(hbuf + swz(m, ucol * 2, 256)) = f2bf(hn);
        }
        if (t < 49) *(uint2*)(xbuf + swz(sr, ss * 8, 256)) = xpf;
        __syncthreads();
    }
#pragma unroll
    for (int j = 0; j < 4; ++j)
        hf[(row0 + lg * 4 + j) * 128 + ucol] = hreg[j];
}

// ---------------- final: BN + 256->256->128->1, MFMA ----------------
__global__ __launch_bounds__(256, 2) void final_mfma(
    const float* __restrict__ hfv, const float* __restrict__ inputs,
    const float* __restrict__ gam, const float* __restrict__ bet,
    const float* __restrict__ mu, const float* __restrict__ var,
    const unsigned short* __restrict__ W1t, const float* __restrict__ b1,
    const unsigned short* __restrict__ W2t, const float* __restrict__ b2,
    const float* __restrict__ fW, const float* __restrict__ fb,
    float* __restrict__ out)
{
    __shared__ __align__(16) unsigned char xnb[16 * 512];  // [16][256] bf16 swz
    __shared__ __align__(16) unsigned char d1b[16 * 512];  // [16][256] bf16 swz
    __shared__ float d2b[16 * 132];
    __shared__ float wfl[128];

    const int tid = threadIdx.x;
    const int wv = tid >> 6, l = tid & 63, l15 = l & 15, lg = l >> 4;
    const size_t r0 = (size_t)blockIdx.x * 16;

    short8 w1f[4][8];
#pragma unroll
    for (int p = 0; p < 4; ++p)
#pragma unroll
        for (int kt = 0; kt < 8; ++kt) {
            int n = wv * 64 + p * 16 + l15;
            w1f[p][kt] = *(const short8*)(W1t + n * 256 + kt * 32 + lg * 8);
        }
    short8 w2f[2][8];
#pragma unroll
    for (int p = 0; p < 2; ++p)
#pragma unroll
        for (int kt = 0; kt < 8; ++kt) {
            int n = wv * 32 + p * 16 + l15;
            w2f[p][kt] = *(const short8*)(W2t + n * 256 + kt * 32 + lg * 8);
        }
    if (tid < 128) wfl[tid] = fW[tid];

    {   // stage BN-normalized input, bf16 swz
        int r = tid >> 4, c = tid & 15, k0 = c * 16;
        float v[16];
#pragma unroll
        for (int q = 0; q < 16; ++q) {
            int k = k0 + q;
            float x = (k < 128) ? hfv[(r0 + r) * 128 + k]
                                : inputs[((r0 + r) * 51 + 50) * 128 + (k - 128)];
            float s = gam[k] * rsqrtf(var[k] + 0.001f);
            v[q] = (x - mu[k]) * s + bet[k];
        }
        U8 t0, t1;
#pragma unroll
        for (int q = 0; q < 8; ++q) { t0.u[q] = f2bf(v[q]); t1.u[q] = f2bf(v[8 + q]); }
        *(short8*)(xnb + swz(r, k0 * 2, 512))      = t0.s;
        *(short8*)(xnb + swz(r, k0 * 2 + 16, 512)) = t1.s;
    }
    __syncthreads();

    // L1: [16][256] @ [256][256], leaky
    f32x4 a1[4];
#pragma unroll
    for (int p = 0; p < 4; ++p) a1[p] = (f32x4){0.f, 0.f, 0.f, 0.f};
#pragma unroll
    for (int kt = 0; kt < 8; ++kt) {
        short8 axx = *(const short8*)(xnb + swz(l15, kt * 64 + lg * 16, 512));
#pragma unroll
        for (int p = 0; p < 4; ++p) a1[p] = mfma16(axx, w1f[p][kt], a1[p]);
    }
#pragma unroll
    for (int p = 0; p < 4; ++p) {
        float bb = b1[wv * 64 + p * 16 + l15];
#pragma unroll
        for (int j = 0; j < 4; ++j) {
            int row = lg * 4 + j, col = wv * 64 + p * 16 + l15;
            *(unsigned short*)(d1b + swz(row, col * 2, 512)) = f2bf(lky(a1[p][j] + bb));
        }
    }
    __syncthreads();

    // L2: [16][256] @ [256][128], leaky
    f32x4 a2[2];
#pragma unroll
    for (int p = 0; p < 2; ++p) a2[p] = (f32x4){0.f, 0.f, 0.f, 0.f};
#pragma unroll
    for (int kt = 0; kt < 8; ++kt) {
        short8 axx = *(const short8*)(d1b + swz(l15, kt * 64 + lg * 16, 512));
#pragma unroll
        for (int p = 0; p < 2; ++p) a2[p] = mfma16(axx, w2f[p][kt], a2[p]);
    }
#pragma unroll
    for (int p = 0; p < 2; ++p) {
        float bb = b2[wv * 32 + p * 16 + l15];
#pragma unroll
        for (int j = 0; j < 4; ++j)
            d2b[(lg * 4 + j) * 132 + wv * 32 + p * 16 + l15] = lky(a2[p][j] + bb);
    }
    __syncthreads();

    if (tid < 16) {
        float s = fb[0];
#pragma unroll 8
        for (int k = 0; k < 128; ++k) s += d2b[tid * 132 + k] * wfl[k];
        out[r0 + tid] = sigf(s);
    }
}

extern "C" void kernel_launch(void* const* d_in, const int* in_sizes, int n_in,
                              void* d_out, int out_size, void* d_ws, size_t ws_size,
                              hipStream_t stream)
{
    const float* inputs   = (const float*)d_in[0];
    const float* gru_W    = (const float*)d_in[1];
    const float* gru_U    = (const float*)d_in[2];
    const float* gru_b    = (const float*)d_in[3];
    const float* att_W1   = (const float*)d_in[4];
    const float* att_b1   = (const float*)d_in[5];
    const float* att_W2   = (const float*)d_in[6];
    const float* att_b2   = (const float*)d_in[7];
    const float* att_W3   = (const float*)d_in[8];
    const float* att_b3   = (const float*)d_in[9];
    const float* au_Wu    = (const float*)d_in[10];
    const float* au_bu    = (const float*)d_in[11];
    const float* au_Uu    = (const float*)d_in[12];
    const float* au_Wr    = (const float*)d_in[13];
    const float* au_br    = (const float*)d_in[14];
    const float* au_Ur    = (const float*)d_in[15];
    const float* au_Wc    = (const float*)d_in[16];
    const float* au_bc    = (const float*)d_in[17];
    const float* au_Uc    = (const float*)d_in[18];
    const float* bn_gamma = (const float*)d_in[19];
    const float* bn_beta  = (const float*)d_in[20];
    const float* bn_mean  = (const float*)d_in[21];
    const float* bn_var   = (const float*)d_in[22];
    const float* d_W1     = (const float*)d_in[23];
    const float* d_b1     = (const float*)d_in[24];
    const float* d_W2     = (const float*)d_in[25];
    const float* d_b2     = (const float*)d_in[26];
    const float* f_W      = (const float*)d_in[27];
    const float* f_b      = (const float*)d_in[28];

    char* w = (char*)d_ws;
    unsigned short* hs  = (unsigned short*)w;
    float* ats          = (float*)(w + 52428800);
    float* hf           = (float*)(w + 53248000);
    float* nterm        = (float*)(w + 55345152);
    unsigned short* Wg  = (unsigned short*)(w + 57442304);
    unsigned short* Ug  = (unsigned short*)(w + 57540608);
    unsigned short* Wau = (unsigned short*)(w + 57638912);
    unsigned short* Uau = (unsigned short*)(w + 57737216);
    unsigned short* WA  = (unsigned short*)(w + 57835520);
    unsigned short* WN  = (unsigned short*)(w + 57901056);
    unsigned short* AW2 = (unsigned short*)(w + 57933824);
    unsigned short* DW1 = (unsigned short*)(w + 57950208);
    unsigned short* DW2 = (unsigned short*)(w + 58081280);
    float* bp           = (float*)(w + 58146816);

    pack_all<<<994, 256, 0, stream>>>(
        gru_W, gru_U, au_Wu, au_Wr, au_Wc, au_Uu, au_Ur, au_Uc,
        att_W1, att_W2, d_W1, d_W2, au_bu, au_br, au_bc,
        Wg, Ug, Wau, Uau, WA, WN, AW2, DW1, DW2, bp);
    nterm_kernel<<<64, 512, 0, stream>>>(inputs, WN, att_b1, nterm);
    gru_mfma<<<256, 512, 0, stream>>>(inputs, Wg, Ug, gru_b, hs);
    attn_mfma<<<3200, 512, 0, stream>>>(hs, inputs, nterm, WA, AW2, att_b2,
                                        att_W3, att_b3, ats);
    augru_mfma<<<256, 512, 0, stream>>>(hs, Wau, Uau, bp, ats, hf);
    final_mfma<<<256, 256, 0, stream>>>(hf, inputs, bn_gamma, bn_beta, bn_mean, bn_var,
                                        DW1, d_b1, DW2, d_b2, f_W, f_b, (float*)d_out);
}

// Round 5
// 232.575 us; speedup vs baseline: 14.0762x; 1.0204x over previous
//
#include <hip/hip_runtime.h>
#include <math.h>

// DIEN bf16-MFMA v3: GRU+attention fused into one persistent recurrence
// (attn pipelined 1-3 steps behind, single barrier per step), AUGRU single-barrier.
// ws layout (bytes) — unchanged from v2:
//  hs_bf16    52,428,800 @ 0
//  ats_f32       819,200 @ 52,428,800
//  hf_f32      2,097,152 @ 53,248,000
//  nterm_f32   2,097,152 @ 55,345,152
//  Wg          98,304 @ 57,442,304   [384][128] bf16
//  Ug          98,304 @ 57,540,608
//  Wau         98,304 @ 57,638,912
//  Uau         98,304 @ 57,737,216
//  WA          65,536 @ 57,835,520   [128][256] bf16 (k<128: W1a-W1b, k>=128: W1d)
//  WN          32,768 @ 57,901,056   [128][128] bf16 (W1b+W1c)
//  AW2         16,384 @ 57,933,824   [64][128] bf16
//  DW1        131,072 @ 57,950,208   [256][256] bf16
//  DW2         65,536 @ 58,081,280   [128][256] bf16
//  bp           1,536 @ 58,146,816   [384] f32

#define LK 0.0003f

typedef __attribute__((ext_vector_type(8))) short short8;
typedef __attribute__((ext_vector_type(4))) float f32x4;

union U8 { short8 s; unsigned short u[8]; };

__device__ __forceinline__ float sigf(float x) { return 1.0f / (1.0f + __expf(-x)); }
__device__ __forceinline__ float tanhfast(float x) { return 2.0f / (1.0f + __expf(-2.0f * x)) - 1.0f; }
__device__ __forceinline__ float lky(float v) { return v >= 0.0f ? v : LK * v; }
__device__ __forceinline__ unsigned short f2bf(float f) {
    unsigned u = __float_as_uint(f);
    return (unsigned short)((u + 0x7FFFu + ((u >> 16) & 1u)) >> 16);
}
__device__ __forceinline__ float bf2f(unsigned short h) {
    return __uint_as_float(((unsigned)h) << 16);
}
// XOR swizzle: 16B-slot permute within 8-row stripes -> <=2-way bank aliasing (free)
__device__ __forceinline__ int swz(int row, int kbyte, int stride) {
    return row * stride + (kbyte ^ ((row & 7) << 4));
}
__device__ __forceinline__ f32x4 mfma16(short8 a, short8 b, f32x4 c) {
    return __builtin_amdgcn_mfma_f32_16x16x32_bf16(a, b, c, 0, 0, 0);
}

// ---------------- pack & transpose all weights to bf16 [n][k] panels ----------------
__global__ void pack_all(
    const float* __restrict__ gW, const float* __restrict__ gU,
    const float* __restrict__ aWu, const float* __restrict__ aWr, const float* __restrict__ aWc,
    const float* __restrict__ aUu, const float* __restrict__ aUr, const float* __restrict__ aUc,
    const float* __restrict__ tW1, const float* __restrict__ tW2,
    const float* __restrict__ dW1, const float* __restrict__ dW2,
    const float* __restrict__ abu, const float* __restrict__ abr, const float* __restrict__ abc,
    unsigned short* __restrict__ Wg, unsigned short* __restrict__ Ug,
    unsigned short* __restrict__ Wau, unsigned short* __restrict__ Uau,
    unsigned short* __restrict__ WA, unsigned short* __restrict__ WN,
    unsigned short* __restrict__ AW2,
    unsigned short* __restrict__ DW1, unsigned short* __restrict__ DW2,
    float* __restrict__ bp)
{
    int i = blockIdx.x * 256 + threadIdx.x;
    if (i < 49152) {                                  // Wg/Ug: [n<384][k<128]
        int n = i >> 7, k = i & 127;
        Wg[i] = f2bf(gW[k * 384 + n]);
        Ug[i] = f2bf(gU[k * 384 + n]);
    } else if (i < 98304) {                           // Wau/Uau
        int j = i - 49152; int n = j >> 7, k = j & 127;
        int g = n >> 7, c = n & 127;
        const float* s = (g == 0) ? aWu : (g == 1) ? aWr : aWc;
        const float* u = (g == 0) ? aUu : (g == 1) ? aUr : aUc;
        Wau[j] = f2bf(s[k * 128 + c]);
        Uau[j] = f2bf(u[k * 128 + c]);
    } else if (i < 131072) {                          // WA: [n<128][k<256]
        int j = i - 98304; int n = j >> 8, k = j & 255;
        float v = (k < 128) ? (tW1[k * 128 + n] - tW1[(128 + k) * 128 + n])
                            : tW1[(384 + (k - 128)) * 128 + n];
        WA[j] = f2bf(v);
    } else if (i < 147456) {                          // WN: [n<128][k<128]
        int j = i - 131072; int n = j >> 7, k = j & 127;
        WN[j] = f2bf(tW1[(128 + k) * 128 + n] + tW1[(256 + k) * 128 + n]);
    } else if (i < 155648) {                          // AW2: [n<64][k<128]
        int j = i - 147456; int n = j >> 7, k = j & 127;
        AW2[j] = f2bf(tW2[k * 64 + n]);
    } else if (i < 221184) {                          // DW1: [n<256][k<256]
        int j = i - 155648; int n = j >> 8, k = j & 255;
        DW1[j] = f2bf(dW1[k * 256 + n]);
    } else if (i < 253952) {                          // DW2: [n<128][k<256]
        int j = i - 221184; int n = j >> 8, k = j & 255;
        DW2[j] = f2bf(dW2[k * 128 + n]);
    } else if (i < 254336) {
        int j = i - 253952;
        bp[j] = (j < 128) ? abu[j] : (j < 256) ? abr[j - 128] : abc[j - 256];
    }
}

// ---------------- nterm = news @ WN + b1  (4096 x 128, K=128) ----------------
__global__ __launch_bounds__(512, 2) void nterm_kernel(
    const float* __restrict__ inputs, const unsigned short* __restrict__ WN,
    const float* __restrict__ b1, float* __restrict__ nterm)
{
    __shared__ __align__(16) unsigned char nb[64 * 256];  // [64][128] bf16 swz

    const int tid = threadIdx.x;
    const int wv = tid >> 6, l = tid & 63, l15 = l & 15, lg = l >> 4;
    const size_t b0 = (size_t)blockIdx.x * 64;

    {
        int r = tid >> 3, c = tid & 7;
        const float* src = inputs + ((b0 + r) * 51 + 50) * 128 + c * 16;
        float4 v0 = *(const float4*)(src);
        float4 v1 = *(const float4*)(src + 4);
        float4 v2 = *(const float4*)(src + 8);
        float4 v3 = *(const float4*)(src + 12);
        U8 t0, t1;
        t0.u[0] = f2bf(v0.x); t0.u[1] = f2bf(v0.y); t0.u[2] = f2bf(v0.z); t0.u[3] = f2bf(v0.w);
        t0.u[4] = f2bf(v1.x); t0.u[5] = f2bf(v1.y); t0.u[6] = f2bf(v1.z); t0.u[7] = f2bf(v1.w);
        t1.u[0] = f2bf(v2.x); t1.u[1] = f2bf(v2.y); t1.u[2] = f2bf(v2.z); t1.u[3] = f2bf(v2.w);
        t1.u[4] = f2bf(v3.x); t1.u[5] = f2bf(v3.y); t1.u[6] = f2bf(v3.z); t1.u[7] = f2bf(v3.w);
        *(short8*)(nb + swz(r, c * 32, 256))      = t0.s;
        *(short8*)(nb + swz(r, c * 32 + 16, 256)) = t1.s;
    }
    __syncthreads();

    short8 wf[4];
#pragma unroll
    for (int kt = 0; kt < 4; ++kt)
        wf[kt] = *(const short8*)(WN + (wv * 16 + l15) * 128 + kt * 32 + lg * 8);

    f32x4 acc[4];
#pragma unroll
    for (int rt = 0; rt < 4; ++rt) acc[rt] = (f32x4){0.f, 0.f, 0.f, 0.f};
#pragma unroll
    for (int rt = 0; rt < 4; ++rt)
#pragma unroll
        for (int kt = 0; kt < 4; ++kt) {
            short8 axx = *(const short8*)(nb + swz(rt * 16 + l15, kt * 64 + lg * 16, 256));
            acc[rt] = mfma16(axx, wf[kt], acc[rt]);
        }
    float bb = b1[wv * 16 + l15];
#pragma unroll
    for (int rt = 0; rt < 4; ++rt)
#pragma unroll
        for (int j = 0; j < 4; ++j)
            nterm[(b0 + rt * 16 + lg * 4 + j) * 128 + wv * 16 + l15] = acc[rt][j] + bb;
}

// ---------------- GRU + attention fused persistent recurrence ----------------
// 512 threads = 8 waves, 16 batch rows/block. One barrier per step.
// Pipeline: step t computes h_t; L1(t-1); L2(t-2); dot->ats(t-3). 3 drain iters.
__global__ __launch_bounds__(512, 2) void gru_attn(
    const float* __restrict__ inputs, const unsigned short* __restrict__ Wt,
    const unsigned short* __restrict__ Ut, const float* __restrict__ gb,
    const unsigned short* __restrict__ WA, const unsigned short* __restrict__ AW2,
    const float* __restrict__ ab2, const float* __restrict__ nterm,
    const float* __restrict__ W3, const float* __restrict__ b3,
    unsigned short* __restrict__ hs, float* __restrict__ ats)
{
    __shared__ __align__(16) unsigned char xbuf[2][4096];   // x_t bf16 [16][128] swz
    __shared__ __align__(16) unsigned char hbuf[2][4096];   // h   bf16 [16][128] swz
    __shared__ __align__(16) unsigned char pbuf[2][4096];   // h*news bf16 swz
    __shared__ __align__(16) unsigned char a1buf[2][4096];  // a1 bf16 [16][128] swz
    __shared__ float a2buf[2][16 * 64];
    __shared__ float w3l[64];

    const int tid = threadIdx.x;
    const int wv = tid >> 6, l = tid & 63, l15 = l & 15, lg = l >> 4;
    const size_t row0 = (size_t)blockIdx.x * 16;
    const int ucol = wv * 16 + l15;            // GRU out col AND attn L1 col

    // --- persistent weight fragments ---
    short8 wf[3][4], uf[3][4];
#pragma unroll
    for (int g = 0; g < 3; ++g)
#pragma unroll
        for (int kt = 0; kt < 4; ++kt) {
            int n = g * 128 + ucol;
            int k0 = kt * 32 + lg * 8;
            wf[g][kt] = *(const short8*)(Wt + n * 128 + k0);
            uf[g][kt] = *(const short8*)(Ut + n * 128 + k0);
        }
    short8 waf[8];
#pragma unroll
    for (int kt = 0; kt < 8; ++kt)
        waf[kt] = *(const short8*)(WA + ucol * 256 + kt * 32 + lg * 8);
    short8 w2f[4];
    const int n2 = (wv & 3) * 16 + l15;
    if (wv < 4) {
#pragma unroll
        for (int kt = 0; kt < 4; ++kt)
            w2f[kt] = *(const short8*)(AW2 + n2 * 128 + kt * 32 + lg * 8);
    }
    const float b2v = (wv < 4) ? ab2[n2] : 0.f;
    const float b3v = b3[0];
    if (tid < 64) w3l[tid] = W3[tid];

    const float bx0 = gb[ucol],       bx1 = gb[128 + ucol], bx2 = gb[256 + ucol];
    const float bh0 = gb[384 + ucol], bh1 = gb[512 + ucol], bh2 = gb[640 + ucol];

    float nt4[4], news4[4];
    size_t hsbase[4];
#pragma unroll
    for (int j = 0; j < 4; ++j) {
        int m = lg * 4 + j;
        nt4[j]   = nterm[(row0 + m) * 128 + ucol];
        news4[j] = inputs[((row0 + m) * 51 + 50) * 128 + ucol];
        hsbase[j] = ((row0 + m) * 50) * 128 + ucol;
    }

    const int sr = tid >> 5, ss = tid & 31;    // x staging: row, 4-elem chunk

    *(uint2*)(hbuf[0] + tid * 8) = make_uint2(0u, 0u);
    {
        float4 v = *(const float4*)&inputs[((row0 + sr) * 51) * 128 + ss * 4];
        unsigned a = (unsigned)f2bf(v.x) | ((unsigned)f2bf(v.y) << 16);
        unsigned b = (unsigned)f2bf(v.z) | ((unsigned)f2bf(v.w) << 16);
        *(uint2*)(xbuf[0] + swz(sr, ss * 8, 256)) = make_uint2(a, b);
    }
    float hreg[4] = {0.f, 0.f, 0.f, 0.f};
    __syncthreads();

    for (int t = 0; t <= 52; ++t) {
        const int p = t & 1;

        float4 xpf;
        if (t < 49) xpf = *(const float4*)&inputs[((row0 + sr) * 51 + (t + 1)) * 128 + ss * 4];

        short8 ah[4];
        if (t <= 50) {
#pragma unroll
            for (int kt = 0; kt < 4; ++kt)
                ah[kt] = *(const short8*)(hbuf[p] + swz(l15, kt * 64 + lg * 16, 256));
        }

        // --- GRU step t ---
        if (t < 50) {
            short8 ax[4];
#pragma unroll
            for (int kt = 0; kt < 4; ++kt)
                ax[kt] = *(const short8*)(xbuf[p] + swz(l15, kt * 64 + lg * 16, 256));
            f32x4 accx[3], acch[3];
#pragma unroll
            for (int g = 0; g < 3; ++g) {
                accx[g] = (f32x4){0.f, 0.f, 0.f, 0.f};
                acch[g] = (f32x4){0.f, 0.f, 0.f, 0.f};
            }
#pragma unroll
            for (int kt = 0; kt < 4; ++kt)
#pragma unroll
                for (int g = 0; g < 3; ++g) {
                    accx[g] = mfma16(ax[kt], wf[g][kt], accx[g]);
                    acch[g] = mfma16(ah[kt], uf[g][kt], acch[g]);
                }
#pragma unroll
            for (int j = 0; j < 4; ++j) {
                int m = lg * 4 + j;
                float z  = sigf(accx[0][j] + acch[0][j] + bx0 + bh0);
                float r  = sigf(accx[1][j] + acch[1][j] + bx1 + bh1);
                float hc = tanhfast(accx[2][j] + bx2 + r * (acch[2][j] + bh2));
                float hn = z * hreg[j] + (1.f - z) * hc;
                hreg[j] = hn;
                unsigned short hb = f2bf(hn);
                *(unsigned short*)(hbuf[p ^ 1] + swz(m, ucol * 2, 256)) = hb;
                *(unsigned short*)(pbuf[p ^ 1] + swz(m, ucol * 2, 256)) = f2bf(hn * news4[j]);
                hs[hsbase[j] + (size_t)t * 128] = hb;
            }
        }

        // --- attn L1 for step t-1 : a1 = relu(h@Wa + p@Wd + nterm) ---
        if (t >= 1 && t <= 50) {
            short8 pa[4];
#pragma unroll
            for (int kt = 0; kt < 4; ++kt)
                pa[kt] = *(const short8*)(pbuf[p] + swz(l15, kt * 64 + lg * 16, 256));
            f32x4 lacc = (f32x4){0.f, 0.f, 0.f, 0.f};
#pragma unroll
            for (int kt = 0; kt < 4; ++kt) lacc = mfma16(ah[kt], waf[kt], lacc);
#pragma unroll
            for (int kt = 0; kt < 4; ++kt) lacc = mfma16(pa[kt], waf[4 + kt], lacc);
#pragma unroll
            for (int j = 0; j < 4; ++j) {
                float v = fmaxf(lacc[j] + nt4[j], 0.f);
                *(unsigned short*)(a1buf[p] + swz(lg * 4 + j, ucol * 2, 256)) = f2bf(v);
            }
        }

        // --- attn L2 for step t-2 : a2 = relu(a1@W2 + b2)  (waves 0-3) ---
        if (t >= 2 && t <= 51 && wv < 4) {
            f32x4 c2 = (f32x4){0.f, 0.f, 0.f, 0.f};
#pragma unroll
            for (int kt = 0; kt < 4; ++kt) {
                short8 aa = *(const short8*)(a1buf[p ^ 1] + swz(l15, kt * 64 + lg * 16, 256));
                c2 = mfma16(aa, w2f[kt], c2);
            }
#pragma unroll
            for (int j = 0; j < 4; ++j)
                a2buf[p][(lg * 4 + j) * 64 + n2] = fmaxf(c2[j] + b2v, 0.f);
        }

        // --- dot for step t-3 : ats = sig(a2.w3 + b3) ---
        if (t >= 3) {
            int rrow = tid >> 5, cc = tid & 31;
            const float* a2r = &a2buf[p ^ 1][rrow * 64];
            float s = a2r[cc] * w3l[cc] + a2r[cc + 32] * w3l[cc + 32];
            s += __shfl_xor(s, 16, 32);
            s += __shfl_xor(s, 8, 32);
            s += __shfl_xor(s, 4, 32);
            s += __shfl_xor(s, 2, 32);
            s += __shfl_xor(s, 1, 32);
            if ((tid & 31) == 0) ats[(row0 + rrow) * 50 + (t - 3)] = sigf(s + b3v);
        }

        if (t < 49) {
            unsigned a = (unsigned)f2bf(xpf.x) | ((unsigned)f2bf(xpf.y) << 16);
            unsigned b = (unsigned)f2bf(xpf.z) | ((unsigned)f2bf(xpf.w) << 16);
            *(uint2*)(xbuf[p ^ 1] + swz(sr, ss * 8, 256)) = make_uint2(a, b);
        }
        __syncthreads();
    }
}

// ---------------- AUGRU: MFMA recurrence, single barrier per step ----------------
__global__ __launch_bounds__(512, 2) void augru_mfma(
    const unsigned short* __restrict__ hsrc, const unsigned short* __restrict__ Wt,
    const unsigned short* __restrict__ Ut, const float* __restrict__ bp,
    const float* __restrict__ ats, float* __restrict__ hf)
{
    __shared__ __align__(16) unsigned char xbuf[2][4096];
    __shared__ __align__(16) unsigned char hbuf[2][4096];

    const int tid = threadIdx.x;
    const int wv = tid >> 6, l = tid & 63, l15 = l & 15, lg = l >> 4;
    const size_t row0 = (size_t)blockIdx.x * 16;
    const int ucol = wv * 16 + l15;

    short8 wf[3][4], uf[3][4];
#pragma unroll
    for (int g = 0; g < 3; ++g)
#pragma unroll
        for (int kt = 0; kt < 4; ++kt) {
            int n = g * 128 + ucol;
            int k0 = kt * 32 + lg * 8;
            wf[g][kt] = *(const short8*)(Wt + n * 128 + k0);
            uf[g][kt] = *(const short8*)(Ut + n * 128 + k0);
        }
    const float bx0 = bp[ucol], bx1 = bp[128 + ucol], bx2 = bp[256 + ucol];

    const int sr = tid >> 5, ss = tid & 31;

    *(uint2*)(hbuf[0] + tid * 8) = make_uint2(0u, 0u);
    {
        uint2 v = *(const uint2*)(hsrc + ((row0 + sr) * 50) * 128 + ss * 4);
        *(uint2*)(xbuf[0] + swz(sr, ss * 8, 256)) = v;
    }
    float hreg[4] = {0.f, 0.f, 0.f, 0.f};
    __syncthreads();

    for (int t = 0; t < 50; ++t) {
        const int p = t & 1;
        uint2 xnext;
        if (t < 49) xnext = *(const uint2*)(hsrc + ((row0 + sr) * 50 + t + 1) * 128 + ss * 4);
        float at4[4];
#pragma unroll
        for (int j = 0; j < 4; ++j) at4[j] = ats[(row0 + lg * 4 + j) * 50 + t];

        short8 ax[4], ah[4];
#pragma unroll
        for (int kt = 0; kt < 4; ++kt) {
            int off = swz(l15, kt * 64 + lg * 16, 256);
            ax[kt] = *(const short8*)(xbuf[p] + off);
            ah[kt] = *(const short8*)(hbuf[p] + off);
        }
        f32x4 accx[3], acch[3];
#pragma unroll
        for (int g = 0; g < 3; ++g) {
            accx[g] = (f32x4){0.f, 0.f, 0.f, 0.f};
            acch[g] = (f32x4){0.f, 0.f, 0.f, 0.f};
        }
#pragma unroll
        for (int kt = 0; kt < 4; ++kt)
#pragma unroll
            for (int g = 0; g < 3; ++g) {
                accx[g] = mfma16(ax[kt], wf[g][kt], accx[g]);
                acch[g] = mfma16(ah[kt], uf[g][kt], acch[g]);
            }
#pragma unroll
        for (int j = 0; j < 4; ++j) {
            int m = lg * 4 + j;
            float u  = sigf(accx[0][j] + bx0 + acch[0][j]);
            float r  = sigf(accx[1][j] + bx1 + acch[1][j]);
            float c  = tanhfast(accx[2][j] + bx2 + r * acch[2][j]);
            float uu = at4[j] * u;
            float hn = (1.f - uu) * hreg[j] + uu * c;
            hreg[j] = hn;
            *(unsigned short*)(hbuf[p ^ 1] + swz(m, ucol * 2, 256)) = f2bf(hn);
        }
        if (t < 49) *(uint2*)(xbuf[p ^ 1] + swz(sr, ss * 8, 256)) = xnext;
        __syncthreads();
    }
#pragma unroll
    for (int j = 0; j < 4; ++j)
        hf[(row0 + lg * 4 + j) * 128 + ucol] = hreg[j];
}

// ---------------- final: BN + 256->256->128->1, MFMA ----------------
__global__ __launch_bounds__(256, 2) void final_mfma(
    const float* __restrict__ hfv, const float* __restrict__ inputs,
    const float* __restrict__ gam, const float* __restrict__ bet,
    const float* __restrict__ mu, const float* __restrict__ var,
    const unsigned short* __restrict__ W1t, const float* __restrict__ b1,
    const unsigned short* __restrict__ W2t, const float* __restrict__ b2,
    const float* __restrict__ fW, const float* __restrict__ fb,
    float* __restrict__ out)
{
    __shared__ __align__(16) unsigned char xnb[16 * 512];  // [16][256] bf16 swz
    __shared__ __align__(16) unsigned char d1b[16 * 512];  // [16][256] bf16 swz
    __shared__ float d2b[16 * 132];
    __shared__ float wfl[128];

    const int tid = threadIdx.x;
    const int wv = tid >> 6, l = tid & 63, l15 = l & 15, lg = l >> 4;
    const size_t r0 = (size_t)blockIdx.x * 16;

    short8 w1f[4][8];
#pragma unroll
    for (int p = 0; p < 4; ++p)
#pragma unroll
        for (int kt = 0; kt < 8; ++kt) {
            int n = wv * 64 + p * 16 + l15;
            w1f[p][kt] = *(const short8*)(W1t + n * 256 + kt * 32 + lg * 8);
        }
    short8 w2f[2][8];
#pragma unroll
    for (int p = 0; p < 2; ++p)
#pragma unroll
        for (int kt = 0; kt < 8; ++kt) {
            int n = wv * 32 + p * 16 + l15;
            w2f[p][kt] = *(const short8*)(W2t + n * 256 + kt * 32 + lg * 8);
        }
    if (tid < 128) wfl[tid] = fW[tid];

    {   // stage BN-normalized input, bf16 swz
        int r = tid >> 4, c = tid & 15, k0 = c * 16;
        float v[16];
#pragma unroll
        for (int q = 0; q < 16; ++q) {
            int k = k0 + q;
            float x = (k < 128) ? hfv[(r0 + r) * 128 + k]
                                : inputs[((r0 + r) * 51 + 50) * 128 + (k - 128)];
            float s = gam[k] * rsqrtf(var[k] + 0.001f);
            v[q] = (x - mu[k]) * s + bet[k];
        }
        U8 t0, t1;
#pragma unroll
        for (int q = 0; q < 8; ++q) { t0.u[q] = f2bf(v[q]); t1.u[q] = f2bf(v[8 + q]); }
        *(short8*)(xnb + swz(r, k0 * 2, 512))      = t0.s;
        *(short8*)(xnb + swz(r, k0 * 2 + 16, 512)) = t1.s;
    }
    __syncthreads();

    // L1: [16][256] @ [256][256], leaky
    f32x4 a1[4];
#pragma unroll
    for (int p = 0; p < 4; ++p) a1[p] = (f32x4){0.f, 0.f, 0.f, 0.f};
#pragma unroll
    for (int kt = 0; kt < 8; ++kt) {
        short8 axx = *(const short8*)(xnb + swz(l15, kt * 64 + lg * 16, 512));
#pragma unroll
        for (int p = 0; p < 4; ++p) a1[p] = mfma16(axx, w1f[p][kt], a1[p]);
    }
#pragma unroll
    for (int p = 0; p < 4; ++p) {
        float bb = b1[wv * 64 + p * 16 + l15];
#pragma unroll
        for (int j = 0; j < 4; ++j) {
            int row = lg * 4 + j, col = wv * 64 + p * 16 + l15;
            *(unsigned short*)(d1b + swz(row, col * 2, 512)) = f2bf(lky(a1[p][j] + bb));
        }
    }
    __syncthreads();

    // L2: [16][256] @ [256][128], leaky
    f32x4 a2[2];
#pragma unroll
    for (int p = 0; p < 2; ++p) a2[p] = (f32x4){0.f, 0.f, 0.f, 0.f};
#pragma unroll
    for (int kt = 0; kt < 8; ++kt) {
        short8 axx = *(const short8*)(d1b + swz(l15, kt * 64 + lg * 16, 512));
#pragma unroll
        for (int p = 0; p < 2; ++p) a2[p] = mfma16(axx, w2f[p][kt], a2[p]);
    }
#pragma unroll
    for (int p = 0; p < 2; ++p) {
        float bb = b2[wv * 32 + p * 16 + l15];
#pragma unroll
        for (int j = 0; j < 4; ++j)
            d2b[(lg * 4 + j) * 132 + wv * 32 + p * 16 + l15] = lky(a2[p][j] + bb);
    }
    __syncthreads();

    if (tid < 16) {
        float s = fb[0];
#pragma unroll 8
        for (int k = 0; k < 128; ++k) s += d2b[tid * 132 + k] * wfl[k];
        out[r0 + tid] = sigf(s);
    }
}

extern "C" void kernel_launch(void* const* d_in, const int* in_sizes, int n_in,
                              void* d_out, int out_size, void* d_ws, size_t ws_size,
                              hipStream_t stream)
{
    const float* inputs   = (const float*)d_in[0];
    const float* gru_W    = (const float*)d_in[1];
    const float* gru_U    = (const float*)d_in[2];
    const float* gru_b    = (const float*)d_in[3];
    const float* att_W1   = (const float*)d_in[4];
    const float* att_b1   = (const float*)d_in[5];
    const float* att_W2   = (const float*)d_in[6];
    const float* att_b2   = (const float*)d_in[7];
    const float* att_W3   = (const float*)d_in[8];
    const float* att_b3   = (const float*)d_in[9];
    const float* au_Wu    = (const float*)d_in[10];
    const float* au_bu    = (const float*)d_in[11];
    const float* au_Uu    = (const float*)d_in[12];
    const float* au_Wr    = (const float*)d_in[13];
    const float* au_br    = (const float*)d_in[14];
    const float* au_Ur    = (const float*)d_in[15];
    const float* au_Wc    = (const float*)d_in[16];
    const float* au_bc    = (const float*)d_in[17];
    const float* au_Uc    = (const float*)d_in[18];
    const float* bn_gamma = (const float*)d_in[19];
    const float* bn_beta  = (const float*)d_in[20];
    const float* bn_mean  = (const float*)d_in[21];
    const float* bn_var   = (const float*)d_in[22];
    const float* d_W1     = (const float*)d_in[23];
    const float* d_b1     = (const float*)d_in[24];
    const float* d_W2     = (const float*)d_in[25];
    const float* d_b2     = (const float*)d_in[26];
    const float* f_W      = (const float*)d_in[27];
    const float* f_b      = (const float*)d_in[28];

    char* w = (char*)d_ws;
    unsigned short* hs  = (unsigned short*)w;
    float* ats          = (float*)(w + 52428800);
    float* hf           = (float*)(w + 53248000);
    float* nterm        = (float*)(w + 55345152);
    unsigned short* Wg  = (unsigned short*)(w + 57442304);
    unsigned short* Ug  = (unsigned short*)(w + 57540608);
    unsigned short* Wau = (unsigned short*)(w + 57638912);
    unsigned short* Uau = (unsigned short*)(w + 57737216);
    unsigned short* WA  = (unsigned short*)(w + 57835520);
    unsigned short* WN  = (unsigned short*)(w + 57901056);
    unsigned short* AW2 = (unsigned short*)(w + 57933824);
    unsigned short* DW1 = (unsigned short*)(w + 57950208);
    unsigned short* DW2 = (unsigned short*)(w + 58081280);
    float* bp           = (float*)(w + 58146816);

    pack_all<<<994, 256, 0, stream>>>(
        gru_W, gru_U, au_Wu, au_Wr, au_Wc, au_Uu, au_Ur, au_Uc,
        att_W1, att_W2, d_W1, d_W2, au_bu, au_br, au_bc,
        Wg, Ug, Wau, Uau, WA, WN, AW2, DW1, DW2, bp);
    nterm_kernel<<<64, 512, 0, stream>>>(inputs, WN, att_b1, nterm);
    gru_attn<<<256, 512, 0, stream>>>(inputs, Wg, Ug, gru_b, WA, AW2, att_b2,
                                      nterm, att_W3, att_b3, hs, ats);
    augru_mfma<<<256, 512, 0, stream>>>(hs, Wau, Uau, bp, ats, hf);
    final_mfma<<<256, 256, 0, stream>>>(hf, inputs, bn_gamma, bn_beta, bn_mean, bn_var,
                                        DW1, d_b1, DW2, d_b2, f_W, f_b, (float*)d_out);
}